// Round 6
// baseline (829.374 us; speedup 1.0000x reference)
//
#include <hip/hip_runtime.h>

#define N_NODES 100000
#define N_EDGES 1600000
#define N_GRAPHS 512
#define MPAD 100096      // 782 * 128
#define COL_CAP 2400000  // N_EDGES + 8*N_NODES worst case
#define NBUCK 782        // buckets of 128 nodes (dst >> 7)
#define BCAP 3072        // per-bucket capacity; mean 2046, sigma ~45 -> 22 sigma margin

typedef unsigned short ushortT;
typedef __attribute__((ext_vector_type(8))) short bf16x8;
typedef __attribute__((ext_vector_type(4))) float f32x4;
typedef __attribute__((ext_vector_type(4))) unsigned int uint4v;

__device__ inline float bf2f(ushortT u) {
    unsigned int x = ((unsigned int)u) << 16;
    return __builtin_bit_cast(float, x);
}
__device__ inline ushortT f2bf(float f) {
    unsigned int x = __builtin_bit_cast(unsigned int, f);
    unsigned int r = (x + 0x7fffu + ((x >> 16) & 1u)) >> 16;
    return (ushortT)r;
}

// ---------------- prep: transpose fp32 weights -> bf16 Wt (fold BN scale), build add vectors ----
__global__ __launch_bounds__(256) void k_prep(
    const float* __restrict__ w11, const float* __restrict__ w12,
    const float* __restrict__ w21, const float* __restrict__ w22,
    const float* __restrict__ w31, const float* __restrict__ w32,
    const float* __restrict__ b11, const float* __restrict__ g1, const float* __restrict__ be1, const float* __restrict__ b12,
    const float* __restrict__ b21, const float* __restrict__ g2, const float* __restrict__ be2, const float* __restrict__ b22,
    const float* __restrict__ b31, const float* __restrict__ g3, const float* __restrict__ be3, const float* __restrict__ b32,
    ushortT* __restrict__ Wt, float* __restrict__ addv)
{
    int bid = blockIdx.x, t = threadIdx.x;
    const float rs = rsqrtf(1.0f + 1e-5f);
    if (bid < 384) {
        int idx = bid * 256 + t;             // 0..98303
        int m = idx >> 14;                   // matrix 0..5
        int r = idx & 16383;
        int k = r & 127;
        int n = r >> 7;
        const float* W = (m == 0) ? w11 : (m == 1) ? w12 : (m == 2) ? w21
                       : (m == 3) ? w22 : (m == 4) ? w31 : w32;
        float v = W[k * 128 + n];
        if ((m & 1) == 0) {                  // a "w1": fold BN scale per out-col n
            const float* gm = (m == 0) ? g1 : (m == 2) ? g2 : g3;
            v *= gm[n] * rs;
        }
        Wt[m * 16384 + n * 128 + k] = f2bf(v);
    } else if (bid == 384) {                 // gemm1 adds: b1*s + beta
        if (t < 384) {
            int L = t >> 7, n = t & 127;
            const float* bb = (L == 0) ? b11 : (L == 1) ? b21 : b31;
            const float* gm = (L == 0) ? g1 : (L == 1) ? g2 : g3;
            const float* be = (L == 0) ? be1 : (L == 1) ? be2 : be3;
            float s = gm[n] * rs;
            addv[(2 * L) * 128 + n] = bb[n] * s + be[n];
        }
    } else {                                 // gemm2 adds: b2
        if (t < 384) {
            int L = t >> 7, n = t & 127;
            const float* bb = (L == 0) ? b12 : (L == 1) ? b22 : b32;
            addv[(2 * L + 1) * 128 + n] = bb[n];
        }
    }
}

// ---------------- x (fp32) -> bf16, plus zeroed padding rows ----------------
__global__ __launch_bounds__(256) void k_cvt(const float* __restrict__ X, ushortT* __restrict__ Y) {
    size_t i = ((size_t)blockIdx.x * 256 + threadIdx.x) * 4;
    if (i >= (size_t)MPAD * 128) return;
    unsigned long long o = 0ull;
    if (i < (size_t)N_NODES * 128) {
        float4 v = *(const float4*)&X[i];
        o = (unsigned long long)f2bf(v.x)
          | ((unsigned long long)f2bf(v.y) << 16)
          | ((unsigned long long)f2bf(v.z) << 32)
          | ((unsigned long long)f2bf(v.w) << 48);
    }
    *(unsigned long long*)&Y[i] = o;
}

// ------- bucket binning: scatter (src,dst) into dst-range buckets, L2-local writes -------
__global__ __launch_bounds__(256) void kb_scatter(const int* __restrict__ src, const int* __restrict__ dst,
                                                  int* __restrict__ gcur, int2* __restrict__ ebin) {
    __shared__ int lcnt[NBUCK];
    __shared__ int lbase[NBUCK];
    int t = threadIdx.x;
    int e0 = blockIdx.x * (N_EDGES / 256);
    int e1 = e0 + (N_EDGES / 256);
    for (int i = t; i < NBUCK; i += 256) lcnt[i] = 0;
    __syncthreads();
    for (int e = e0 + t; e < e1; e += 256) atomicAdd(&lcnt[dst[e] >> 7], 1);
    __syncthreads();
    for (int i = t; i < NBUCK; i += 256) {
        int c = lcnt[i];
        lbase[i] = c ? atomicAdd(&gcur[i], c) : 0;
    }
    __syncthreads();
    for (int i = t; i < NBUCK; i += 256) lcnt[i] = 0;
    __syncthreads();
    for (int e = e0 + t; e < e1; e += 256) {
        int d = dst[e];
        int b = d >> 7;
        int off = atomicAdd(&lcnt[b], 1);
        ebin[(size_t)b * BCAP + lbase[b] + off] = make_int2(src[e], d);
    }
}

// ------- per-bucket degree count: LDS histogram, no global atomics -------
__global__ __launch_bounds__(256) void kb_count(const int2* __restrict__ ebin, const int* __restrict__ gcur,
                                                int* __restrict__ deg) {
    __shared__ int cnt[128];
    int b = blockIdx.x, t = threadIdx.x;
    if (t < 128) cnt[t] = 0;
    __syncthreads();
    int m = gcur[b];
    const int2* eb = ebin + (size_t)b * BCAP;
    for (int e = t; e < m; e += 256) atomicAdd(&cnt[eb[e].y & 127], 1);
    __syncthreads();
    if (t < 128) {
        int node = b * 128 + t;
        if (node < N_NODES) deg[node] = cnt[t];
    }
}

__global__ __launch_bounds__(1024) void k_scan1(const int* __restrict__ deg, int* __restrict__ tscan,
                                                int* __restrict__ bsum) {
    __shared__ int s[1024];
    int t = threadIdx.x;
    int i = blockIdx.x * 1024 + t;
    int v = (i < N_NODES) ? ((deg[i] + 7) & ~7) : 0;   // padded degree
    s[t] = v;
    __syncthreads();
    for (int off = 1; off < 1024; off <<= 1) {
        int tmp = (t >= off) ? s[t - off] : 0;
        __syncthreads();
        s[t] += tmp;
        __syncthreads();
    }
    tscan[i] = s[t];
    if (t == 1023) bsum[blockIdx.x] = s[1023];
}

__global__ void k_scan2(const int* __restrict__ bsum, int* __restrict__ boff) {
    if (threadIdx.x == 0 && blockIdx.x == 0) {
        int run = 0;
        for (int b = 0; b < 98; ++b) { boff[b] = run; run += bsum[b]; }
    }
}

__global__ __launch_bounds__(256) void k_scan3(const int* __restrict__ tscan, const int* __restrict__ boff,
                                               int* __restrict__ pstart) {
    int i = blockIdx.x * 256 + threadIdx.x;
    if (i > N_NODES) return;
    pstart[i] = (i == 0) ? 0 : tscan[i - 1] + boff[(i - 1) >> 10];
}

// ------- per-bucket CSR fill: LDS cursors, writes confined to bucket's CSR window -------
__global__ __launch_bounds__(256) void kb_fill(const int2* __restrict__ ebin, const int* __restrict__ gcur,
                                               const int* __restrict__ pstart, int* __restrict__ col) {
    __shared__ int ps[128];
    __shared__ int cur[128];
    int b = blockIdx.x, t = threadIdx.x;
    if (t < 128) {
        int node = b * 128 + t;
        ps[t] = (node < N_NODES) ? pstart[node] : 0;
        cur[t] = 0;
    }
    __syncthreads();
    int m = gcur[b];
    const int2* eb = ebin + (size_t)b * BCAP;
    for (int e = t; e < m; e += 256) {
        int2 sd = eb[e];
        int idx = sd.y & 127;
        int pos = ps[idx] + atomicAdd(&cur[idx], 1);
        col[pos] = sd.x;
    }
}

// pad each node's list up to multiple of 8 with index N_NODES (a guaranteed-zero row)
__global__ __launch_bounds__(256) void k_padfill(const int* __restrict__ deg, const int* __restrict__ pstart,
                                                 int* __restrict__ col) {
    int i = blockIdx.x * 256 + threadIdx.x;
    if (i >= N_NODES) return;
    int s = pstart[i] + deg[i];
    int e = pstart[i + 1];
    for (int j = s; j < e; ++j) col[j] = N_NODES;
}

// ======== FUSED LAYER: per wave (32 rows): gather-agg -> LDS -> gemm1 -> relu -> LDS
// ======== -> gemm2 -> relu -> store. Wave-local LDS window => NO barriers at all.
__global__ __launch_bounds__(256, 3) void k_layer(
    const ushortT* __restrict__ X, const int* __restrict__ pstart, const int* __restrict__ col,
    const ushortT* __restrict__ W1, const float* __restrict__ add1,
    const ushortT* __restrict__ W2, const float* __restrict__ add2,
    ushortT* __restrict__ C)
{
    __shared__ ushortT tile[128 * 136];      // 4 waves x 32 rows, stride 136 (2-way alias only)
    int tid = threadIdx.x;
    int wave = tid >> 6, lane = tid & 63;
    int quad = lane >> 4, l16 = lane & 15;
    int base = blockIdx.x * 128 + wave * 32; // this wave's 32-row window
    ushortT* wt = tile + (wave * 32) * 136;

    // ---- phase 1: gather-aggregate 32 nodes into wave-local LDS ----
    for (int ln = 0; ln < 32; ++ln) {
        int node = base + ln;
        float ax = 0.f, ay = 0.f;
        if (node < N_NODES) {
            int lo = pstart[node], hi = pstart[node + 1];
            unsigned int v = *(const unsigned int*)&X[(size_t)node * 128 + lane * 2];
            ax = bf2f((ushortT)(v & 0xffff));
            ay = bf2f((ushortT)(v >> 16));
            for (int j = lo; j < hi; j += 8) {   // degree padded to x8
                int4 c0 = *(const int4*)&col[j];
                int4 c1 = *(const int4*)&col[j + 4];
                unsigned int u0 = *(const unsigned int*)&X[(size_t)c0.x * 128 + lane * 2];
                unsigned int u1 = *(const unsigned int*)&X[(size_t)c0.y * 128 + lane * 2];
                unsigned int u2 = *(const unsigned int*)&X[(size_t)c0.z * 128 + lane * 2];
                unsigned int u3 = *(const unsigned int*)&X[(size_t)c0.w * 128 + lane * 2];
                unsigned int u4 = *(const unsigned int*)&X[(size_t)c1.x * 128 + lane * 2];
                unsigned int u5 = *(const unsigned int*)&X[(size_t)c1.y * 128 + lane * 2];
                unsigned int u6 = *(const unsigned int*)&X[(size_t)c1.z * 128 + lane * 2];
                unsigned int u7 = *(const unsigned int*)&X[(size_t)c1.w * 128 + lane * 2];
                ax += bf2f((ushortT)(u0 & 0xffff)) + bf2f((ushortT)(u1 & 0xffff))
                    + bf2f((ushortT)(u2 & 0xffff)) + bf2f((ushortT)(u3 & 0xffff))
                    + bf2f((ushortT)(u4 & 0xffff)) + bf2f((ushortT)(u5 & 0xffff))
                    + bf2f((ushortT)(u6 & 0xffff)) + bf2f((ushortT)(u7 & 0xffff));
                ay += bf2f((ushortT)(u0 >> 16)) + bf2f((ushortT)(u1 >> 16))
                    + bf2f((ushortT)(u2 >> 16)) + bf2f((ushortT)(u3 >> 16))
                    + bf2f((ushortT)(u4 >> 16)) + bf2f((ushortT)(u5 >> 16))
                    + bf2f((ushortT)(u6 >> 16)) + bf2f((ushortT)(u7 >> 16));
            }
        }
        unsigned int o = ((unsigned int)f2bf(ay) << 16) | (unsigned int)f2bf(ax);
        *(unsigned int*)&wt[ln * 136 + lane * 2] = o;
    }

    // ---- phase 2: gemm1 on the wave's 32 rows (A from LDS, B streamed from L2) ----
    f32x4 acc[2][8];
#pragma unroll
    for (int t2 = 0; t2 < 2; ++t2)
#pragma unroll
        for (int c = 0; c < 8; ++c) acc[t2][c] = (f32x4){0.f, 0.f, 0.f, 0.f};
    bf16x8 af[2][4];
#pragma unroll
    for (int t2 = 0; t2 < 2; ++t2)
#pragma unroll
        for (int kc = 0; kc < 4; ++kc)
            af[t2][kc] = *(const bf16x8*)&wt[(t2 * 16 + l16) * 136 + kc * 32 + quad * 8];
#pragma unroll
    for (int kc = 0; kc < 4; ++kc) {
#pragma unroll
        for (int c = 0; c < 8; ++c) {
            bf16x8 b1 = *(const bf16x8*)&W1[(c * 16 + l16) * 128 + kc * 32 + quad * 8];
            acc[0][c] = __builtin_amdgcn_mfma_f32_16x16x32_bf16(af[0][kc], b1, acc[0][c], 0, 0, 0);
            acc[1][c] = __builtin_amdgcn_mfma_f32_16x16x32_bf16(af[1][kc], b1, acc[1][c], 0, 0, 0);
        }
    }

    // ---- H = relu(acc + add1) back into the same wave-local LDS window ----
#pragma unroll
    for (int t2 = 0; t2 < 2; ++t2) {
#pragma unroll
        for (int c = 0; c < 8; ++c) {
            int n = c * 16 + l16;
            float ad = add1[n];
#pragma unroll
            for (int r = 0; r < 4; ++r) {
                float y = acc[t2][c][r] + ad;
                y = y > 0.f ? y : 0.f;
                wt[(t2 * 16 + quad * 4 + r) * 136 + n] = f2bf(y);
            }
        }
    }

    // ---- phase 3: gemm2 ----
#pragma unroll
    for (int t2 = 0; t2 < 2; ++t2)
#pragma unroll
        for (int c = 0; c < 8; ++c) acc[t2][c] = (f32x4){0.f, 0.f, 0.f, 0.f};
#pragma unroll
    for (int t2 = 0; t2 < 2; ++t2)
#pragma unroll
        for (int kc = 0; kc < 4; ++kc)
            af[t2][kc] = *(const bf16x8*)&wt[(t2 * 16 + l16) * 136 + kc * 32 + quad * 8];
#pragma unroll
    for (int kc = 0; kc < 4; ++kc) {
#pragma unroll
        for (int c = 0; c < 8; ++c) {
            bf16x8 b2 = *(const bf16x8*)&W2[(c * 16 + l16) * 128 + kc * 32 + quad * 8];
            acc[0][c] = __builtin_amdgcn_mfma_f32_16x16x32_bf16(af[0][kc], b2, acc[0][c], 0, 0, 0);
            acc[1][c] = __builtin_amdgcn_mfma_f32_16x16x32_bf16(af[1][kc], b2, acc[1][c], 0, 0, 0);
        }
    }

    // ---- epilogue: C = relu(acc + add2), store ----
#pragma unroll
    for (int t2 = 0; t2 < 2; ++t2) {
#pragma unroll
        for (int c = 0; c < 8; ++c) {
            int n = c * 16 + l16;
            float ad = add2[n];
#pragma unroll
            for (int r = 0; r < 4; ++r) {
                int row = base + t2 * 16 + quad * 4 + r;
                if (row < N_NODES) {
                    float y = acc[t2][c][r] + ad;
                    y = y > 0.f ? y : 0.f;
                    C[(size_t)row * 128 + n] = f2bf(y);
                }
            }
        }
    }
}

// ------- pooling: wave-per-row-slice run-length accumulation, unroll-4 -------
#define POOL_CHUNK 512
__global__ __launch_bounds__(256) void k_pool(const ushortT* __restrict__ H, const int* __restrict__ batch,
                                              float* __restrict__ P, int off) {
    int n0 = blockIdx.x * POOL_CHUNK;
    int lane = threadIdx.x & 63;
    int s = threadIdx.x >> 6;                // 4 interleaved node streams (one per wave)
    int d2 = lane * 2;                       // two dims per thread
    int end = n0 + POOL_CHUNK;
    if (end > N_NODES) end = N_NODES;
    float ax = 0.f, ay = 0.f;
    int cur = -1;
    int i = n0 + s;
    for (; i + 12 < end; i += 16) {
        int g0 = batch[i], g1 = batch[i + 4], g2 = batch[i + 8], g3 = batch[i + 12];
        unsigned int u0 = *(const unsigned int*)&H[(size_t)i * 128 + d2];
        unsigned int u1 = *(const unsigned int*)&H[(size_t)(i + 4) * 128 + d2];
        unsigned int u2 = *(const unsigned int*)&H[(size_t)(i + 8) * 128 + d2];
        unsigned int u3 = *(const unsigned int*)&H[(size_t)(i + 12) * 128 + d2];
        int gs[4] = {g0, g1, g2, g3};
        unsigned int us[4] = {u0, u1, u2, u3};
#pragma unroll
        for (int q = 0; q < 4; ++q) {
            if (gs[q] != cur) {
                if (cur >= 0) {
                    atomicAdd(&P[cur * 384 + off + d2], ax);
                    atomicAdd(&P[cur * 384 + off + d2 + 1], ay);
                }
                cur = gs[q];
                ax = 0.f; ay = 0.f;
            }
            ax += bf2f((ushortT)(us[q] & 0xffff));
            ay += bf2f((ushortT)(us[q] >> 16));
        }
    }
    for (; i < end; i += 4) {
        int gi = batch[i];
        unsigned int u = *(const unsigned int*)&H[(size_t)i * 128 + d2];
        if (gi != cur) {
            if (cur >= 0) {
                atomicAdd(&P[cur * 384 + off + d2], ax);
                atomicAdd(&P[cur * 384 + off + d2 + 1], ay);
            }
            cur = gi;
            ax = 0.f; ay = 0.f;
        }
        ax += bf2f((ushortT)(u & 0xffff));
        ay += bf2f((ushortT)(u >> 16));
    }
    if (cur >= 0) {
        atomicAdd(&P[cur * 384 + off + d2], ax);
        atomicAdd(&P[cur * 384 + off + d2 + 1], ay);
    }
}

// ---------------- head: out = relu(P @ W1 + b1) @ W2 + b2  (all fp32) ------------
__global__ __launch_bounds__(384) void k_head(const float* __restrict__ P, const float* __restrict__ W1,
                                              const float* __restrict__ B1, const float* __restrict__ W2,
                                              const float* __restrict__ B2, float* __restrict__ out) {
    __shared__ float pr[384];
    __shared__ float qr[384];
    int g = blockIdx.x, t = threadIdx.x;
    pr[t] = P[g * 384 + t];
    __syncthreads();
    float a = 0.f;
    for (int k = 0; k < 384; ++k) a += pr[k] * W1[k * 384 + t];
    a += B1[t];
    qr[t] = a > 0.f ? a : 0.f;
    __syncthreads();
    if (t < 10) {
        float o = 0.f;
        for (int k = 0; k < 384; ++k) o += qr[k] * W2[k * 10 + t];
        o += B2[t];
        out[g * 10 + t] = o;
    }
}

extern "C" void kernel_launch(void* const* d_in, const int* in_sizes, int n_in,
                              void* d_out, int out_size, void* d_ws, size_t ws_size,
                              hipStream_t stream) {
    const float* x     = (const float*)d_in[0];
    const int*   ei    = (const int*)d_in[1];
    const int*   srcA  = ei;
    const int*   dstA  = ei + N_EDGES;
    const int*   batch = (const int*)d_in[2];
    const float* c1_w1 = (const float*)d_in[3];
    const float* c1_b1 = (const float*)d_in[4];
    const float* c1_g  = (const float*)d_in[5];
    const float* c1_be = (const float*)d_in[6];
    const float* c1_w2 = (const float*)d_in[7];
    const float* c1_b2 = (const float*)d_in[8];
    const float* c2_w1 = (const float*)d_in[9];
    const float* c2_b1 = (const float*)d_in[10];
    const float* c2_g  = (const float*)d_in[11];
    const float* c2_be = (const float*)d_in[12];
    const float* c2_w2 = (const float*)d_in[13];
    const float* c2_b2 = (const float*)d_in[14];
    const float* c3_w1 = (const float*)d_in[15];
    const float* c3_b1 = (const float*)d_in[16];
    const float* c3_g  = (const float*)d_in[17];
    const float* c3_be = (const float*)d_in[18];
    const float* c3_w2 = (const float*)d_in[19];
    const float* c3_b2 = (const float*)d_in[20];
    const float* l1w   = (const float*)d_in[21];
    const float* l1b   = (const float*)d_in[22];
    const float* l2w   = (const float*)d_in[23];
    const float* l2b   = (const float*)d_in[24];
    float* out = (float*)d_out;

    size_t o = 0;
    char* base = (char*)d_ws;
    auto alloc = [&](size_t n) -> char* {
        char* p = base + o;
        o += (n + 255) & ~(size_t)255;
        return p;
    };
    ushortT* Wt    = (ushortT*)alloc(6 * 16384 * 2);
    float*   addv  = (float*)alloc(6 * 128 * 4);
    int*     deg   = (int*)alloc((size_t)N_NODES * 4);
    int*     gcur  = (int*)alloc((size_t)NBUCK * 4);
    int*     tscan = (int*)alloc((size_t)100352 * 4);
    int*     bsum  = (int*)alloc(98 * 4);
    int*     boff  = (int*)alloc(98 * 4);
    int*     pst   = (int*)alloc((size_t)(N_NODES + 1) * 4);
    int*     colA  = (int*)alloc((size_t)COL_CAP * 4);
    ushortT* bufA  = (ushortT*)alloc((size_t)MPAD * 128 * 2);   // L0/L2 out; ebin aliases this
    ushortT* bufB  = (ushortT*)alloc((size_t)MPAD * 128 * 2);   // L1 out
    ushortT* bufC  = (ushortT*)alloc((size_t)MPAD * 128 * 2);   // x(bf16)
    float*   pbuf  = (float*)alloc((size_t)N_GRAPHS * 384 * 4);
    int2*    ebin  = (int2*)bufA;   // 782*3072*8 = 19.2 MB <= 25.6 MB; dead before layer 0 runs

    hipMemsetAsync(gcur, 0, (size_t)NBUCK * 4, stream);
    hipMemsetAsync(pbuf, 0, (size_t)N_GRAPHS * 384 * 4, stream);
    // gather pad row (index N_NODES) must be zero in every buffer used as gather input
    hipMemsetAsync(bufB + (size_t)N_NODES * 128, 0, 256, stream);

    k_prep<<<386, 256, 0, stream>>>(c1_w1, c1_w2, c2_w1, c2_w2, c3_w1, c3_w2,
                                    c1_b1, c1_g, c1_be, c1_b2,
                                    c2_b1, c2_g, c2_be, c2_b2,
                                    c3_b1, c3_g, c3_be, c3_b2,
                                    Wt, addv);
    k_cvt<<<(MPAD * 128 / 4 + 255) / 256, 256, 0, stream>>>(x, bufC);
    kb_scatter<<<256, 256, 0, stream>>>(srcA, dstA, gcur, ebin);
    kb_count<<<NBUCK, 256, 0, stream>>>(ebin, gcur, deg);
    k_scan1<<<98, 1024, 0, stream>>>(deg, tscan, bsum);
    k_scan2<<<1, 64, 0, stream>>>(bsum, boff);
    k_scan3<<<391, 256, 0, stream>>>(tscan, boff, pst);
    kb_fill<<<NBUCK, 256, 0, stream>>>(ebin, gcur, pst, colA);
    k_padfill<<<391, 256, 0, stream>>>(deg, pst, colA);
    // ebin (aliasing bufA) is dead from here; zero bufA's pad row before it's used as gather input
    hipMemsetAsync(bufA + (size_t)N_NODES * 128, 0, 256, stream);

    // layer 0: bufC -> bufA ; layer 1: bufA -> bufB ; layer 2: bufB -> bufA
    k_layer<<<NBUCK, 256, 0, stream>>>(bufC, pst, colA, Wt + 0 * 16384, addv + 0 * 128,
                                       Wt + 1 * 16384, addv + 1 * 128, bufA);
    k_pool<<<(N_NODES + POOL_CHUNK - 1) / POOL_CHUNK, 256, 0, stream>>>(bufA, batch, pbuf, 0);
    k_layer<<<NBUCK, 256, 0, stream>>>(bufA, pst, colA, Wt + 2 * 16384, addv + 2 * 128,
                                       Wt + 3 * 16384, addv + 3 * 128, bufB);
    k_pool<<<(N_NODES + POOL_CHUNK - 1) / POOL_CHUNK, 256, 0, stream>>>(bufB, batch, pbuf, 128);
    k_layer<<<NBUCK, 256, 0, stream>>>(bufB, pst, colA, Wt + 4 * 16384, addv + 4 * 128,
                                       Wt + 5 * 16384, addv + 5 * 128, bufA);
    k_pool<<<(N_NODES + POOL_CHUNK - 1) / POOL_CHUNK, 256, 0, stream>>>(bufA, batch, pbuf, 256);

    k_head<<<N_GRAPHS, 384, 0, stream>>>(pbuf, l1w, l1b, l2w, l2b, out);
}

// Round 7
// 647.908 us; speedup vs baseline: 1.2801x; 1.2801x over previous
//
#include <hip/hip_runtime.h>

#define N_NODES 100000
#define N_EDGES 1600000
#define N_GRAPHS 512
#define MPAD 100096      // 782 * 128
#define COL_CAP 2400000  // N_EDGES + 8*N_NODES worst case
#define NBUCK 782        // buckets of 128 nodes (dst >> 7)
#define BCAP 3072        // per-bucket capacity; mean 2046, sigma ~45 -> 22 sigma margin

typedef unsigned short ushortT;
typedef __attribute__((ext_vector_type(8))) short bf16x8;
typedef __attribute__((ext_vector_type(4))) float f32x4;
typedef __attribute__((ext_vector_type(4))) unsigned int uint4v;

__device__ inline float bf2f(ushortT u) {
    unsigned int x = ((unsigned int)u) << 16;
    return __builtin_bit_cast(float, x);
}
__device__ inline ushortT f2bf(float f) {
    unsigned int x = __builtin_bit_cast(unsigned int, f);
    unsigned int r = (x + 0x7fffu + ((x >> 16) & 1u)) >> 16;
    return (ushortT)r;
}

// ---------------- prep: transpose fp32 weights -> bf16 Wt (fold BN scale), build add vectors ----
__global__ __launch_bounds__(256) void k_prep(
    const float* __restrict__ w11, const float* __restrict__ w12,
    const float* __restrict__ w21, const float* __restrict__ w22,
    const float* __restrict__ w31, const float* __restrict__ w32,
    const float* __restrict__ b11, const float* __restrict__ g1, const float* __restrict__ be1, const float* __restrict__ b12,
    const float* __restrict__ b21, const float* __restrict__ g2, const float* __restrict__ be2, const float* __restrict__ b22,
    const float* __restrict__ b31, const float* __restrict__ g3, const float* __restrict__ be3, const float* __restrict__ b32,
    ushortT* __restrict__ Wt, float* __restrict__ addv)
{
    int bid = blockIdx.x, t = threadIdx.x;
    const float rs = rsqrtf(1.0f + 1e-5f);
    if (bid < 384) {
        int idx = bid * 256 + t;             // 0..98303
        int m = idx >> 14;                   // matrix 0..5
        int r = idx & 16383;
        int k = r & 127;
        int n = r >> 7;
        const float* W = (m == 0) ? w11 : (m == 1) ? w12 : (m == 2) ? w21
                       : (m == 3) ? w22 : (m == 4) ? w31 : w32;
        float v = W[k * 128 + n];
        if ((m & 1) == 0) {                  // a "w1": fold BN scale per out-col n
            const float* gm = (m == 0) ? g1 : (m == 2) ? g2 : g3;
            v *= gm[n] * rs;
        }
        Wt[m * 16384 + n * 128 + k] = f2bf(v);
    } else if (bid == 384) {                 // gemm1 adds: b1*s + beta
        if (t < 384) {
            int L = t >> 7, n = t & 127;
            const float* bb = (L == 0) ? b11 : (L == 1) ? b21 : b31;
            const float* gm = (L == 0) ? g1 : (L == 1) ? g2 : g3;
            const float* be = (L == 0) ? be1 : (L == 1) ? be2 : be3;
            float s = gm[n] * rs;
            addv[(2 * L) * 128 + n] = bb[n] * s + be[n];
        }
    } else {                                 // gemm2 adds: b2
        if (t < 384) {
            int L = t >> 7, n = t & 127;
            const float* bb = (L == 0) ? b12 : (L == 1) ? b22 : b32;
            addv[(2 * L + 1) * 128 + n] = bb[n];
        }
    }
}

// ---------------- x (fp32) -> bf16, plus zeroed padding rows ----------------
__global__ __launch_bounds__(256) void k_cvt(const float* __restrict__ X, ushortT* __restrict__ Y) {
    size_t i = ((size_t)blockIdx.x * 256 + threadIdx.x) * 4;
    if (i >= (size_t)MPAD * 128) return;
    unsigned long long o = 0ull;
    if (i < (size_t)N_NODES * 128) {
        float4 v = *(const float4*)&X[i];
        o = (unsigned long long)f2bf(v.x)
          | ((unsigned long long)f2bf(v.y) << 16)
          | ((unsigned long long)f2bf(v.z) << 32)
          | ((unsigned long long)f2bf(v.w) << 48);
    }
    *(unsigned long long*)&Y[i] = o;
}

// ------- bucket binning: scatter (src,dst) into dst-range buckets, L2-local writes -------
__global__ __launch_bounds__(256) void kb_scatter(const int* __restrict__ src, const int* __restrict__ dst,
                                                  int* __restrict__ gcur, int2* __restrict__ ebin) {
    __shared__ int lcnt[NBUCK];
    __shared__ int lbase[NBUCK];
    int t = threadIdx.x;
    int e0 = blockIdx.x * (N_EDGES / 256);
    int e1 = e0 + (N_EDGES / 256);
    for (int i = t; i < NBUCK; i += 256) lcnt[i] = 0;
    __syncthreads();
    for (int e = e0 + t; e < e1; e += 256) atomicAdd(&lcnt[dst[e] >> 7], 1);
    __syncthreads();
    for (int i = t; i < NBUCK; i += 256) {
        int c = lcnt[i];
        lbase[i] = c ? atomicAdd(&gcur[i], c) : 0;
    }
    __syncthreads();
    for (int i = t; i < NBUCK; i += 256) lcnt[i] = 0;
    __syncthreads();
    for (int e = e0 + t; e < e1; e += 256) {
        int d = dst[e];
        int b = d >> 7;
        int off = atomicAdd(&lcnt[b], 1);
        ebin[(size_t)b * BCAP + lbase[b] + off] = make_int2(src[e], d);
    }
}

// ------- per-bucket degree count: LDS histogram, no global atomics -------
__global__ __launch_bounds__(256) void kb_count(const int2* __restrict__ ebin, const int* __restrict__ gcur,
                                                int* __restrict__ deg) {
    __shared__ int cnt[128];
    int b = blockIdx.x, t = threadIdx.x;
    if (t < 128) cnt[t] = 0;
    __syncthreads();
    int m = gcur[b];
    const int2* eb = ebin + (size_t)b * BCAP;
    for (int e = t; e < m; e += 256) atomicAdd(&cnt[eb[e].y & 127], 1);
    __syncthreads();
    if (t < 128) {
        int node = b * 128 + t;
        if (node < N_NODES) deg[node] = cnt[t];
    }
}

__global__ __launch_bounds__(1024) void k_scan1(const int* __restrict__ deg, int* __restrict__ tscan,
                                                int* __restrict__ bsum) {
    __shared__ int s[1024];
    int t = threadIdx.x;
    int i = blockIdx.x * 1024 + t;
    int v = (i < N_NODES) ? ((deg[i] + 7) & ~7) : 0;   // padded degree
    s[t] = v;
    __syncthreads();
    for (int off = 1; off < 1024; off <<= 1) {
        int tmp = (t >= off) ? s[t - off] : 0;
        __syncthreads();
        s[t] += tmp;
        __syncthreads();
    }
    tscan[i] = s[t];
    if (t == 1023) bsum[blockIdx.x] = s[1023];
}

__global__ void k_scan2(const int* __restrict__ bsum, int* __restrict__ boff) {
    if (threadIdx.x == 0 && blockIdx.x == 0) {
        int run = 0;
        for (int b = 0; b < 98; ++b) { boff[b] = run; run += bsum[b]; }
    }
}

__global__ __launch_bounds__(256) void k_scan3(const int* __restrict__ tscan, const int* __restrict__ boff,
                                               int* __restrict__ pstart) {
    int i = blockIdx.x * 256 + threadIdx.x;
    if (i > N_NODES) return;
    pstart[i] = (i == 0) ? 0 : tscan[i - 1] + boff[(i - 1) >> 10];
}

// ------- per-bucket CSR fill: LDS cursors, writes confined to bucket's CSR window -------
__global__ __launch_bounds__(256) void kb_fill(const int2* __restrict__ ebin, const int* __restrict__ gcur,
                                               const int* __restrict__ pstart, int* __restrict__ col) {
    __shared__ int ps[128];
    __shared__ int cur[128];
    int b = blockIdx.x, t = threadIdx.x;
    if (t < 128) {
        int node = b * 128 + t;
        ps[t] = (node < N_NODES) ? pstart[node] : 0;
        cur[t] = 0;
    }
    __syncthreads();
    int m = gcur[b];
    const int2* eb = ebin + (size_t)b * BCAP;
    for (int e = t; e < m; e += 256) {
        int2 sd = eb[e];
        int idx = sd.y & 127;
        int pos = ps[idx] + atomicAdd(&cur[idx], 1);
        col[pos] = sd.x;
    }
}

// pad each node's list up to multiple of 8 with index N_NODES (a guaranteed-zero row)
__global__ __launch_bounds__(256) void k_padfill(const int* __restrict__ deg, const int* __restrict__ pstart,
                                                 int* __restrict__ col) {
    int i = blockIdx.x * 256 + threadIdx.x;
    if (i >= N_NODES) return;
    int s = pstart[i] + deg[i];
    int e = pstart[i + 1];
    for (int j = s; j < e; ++j) col[j] = N_NODES;
}

// ------- aggregation (bf16): T[i] = bf16(X[i] + sum_j X[col[j]]), unroll-8 branch-free -------
__global__ __launch_bounds__(256) void k_agg(const ushortT* __restrict__ X, const int* __restrict__ pstart,
                                             const int* __restrict__ col, ushortT* __restrict__ T) {
    int gid = blockIdx.x * 4 + (threadIdx.x >> 6);
    int lane = threadIdx.x & 63;
    if (gid >= MPAD) return;
    if (gid >= N_NODES) {                    // zero padding rows (MFMA A-operand hygiene)
        *(unsigned int*)&T[(size_t)gid * 128 + lane * 2] = 0u;
        return;
    }
    int lo = pstart[gid], hi = pstart[gid + 1];
    unsigned int v = *(const unsigned int*)&X[(size_t)gid * 128 + lane * 2];
    float ax = bf2f((ushortT)(v & 0xffff));
    float ay = bf2f((ushortT)(v >> 16));
    for (int j = lo; j < hi; j += 8) {       // (hi-lo) % 8 == 0 by construction
        int4 c0 = *(const int4*)&col[j];
        int4 c1 = *(const int4*)&col[j + 4];
        unsigned int u0 = *(const unsigned int*)&X[(size_t)c0.x * 128 + lane * 2];
        unsigned int u1 = *(const unsigned int*)&X[(size_t)c0.y * 128 + lane * 2];
        unsigned int u2 = *(const unsigned int*)&X[(size_t)c0.z * 128 + lane * 2];
        unsigned int u3 = *(const unsigned int*)&X[(size_t)c0.w * 128 + lane * 2];
        unsigned int u4 = *(const unsigned int*)&X[(size_t)c1.x * 128 + lane * 2];
        unsigned int u5 = *(const unsigned int*)&X[(size_t)c1.y * 128 + lane * 2];
        unsigned int u6 = *(const unsigned int*)&X[(size_t)c1.z * 128 + lane * 2];
        unsigned int u7 = *(const unsigned int*)&X[(size_t)c1.w * 128 + lane * 2];
        ax += bf2f((ushortT)(u0 & 0xffff)) + bf2f((ushortT)(u1 & 0xffff))
            + bf2f((ushortT)(u2 & 0xffff)) + bf2f((ushortT)(u3 & 0xffff))
            + bf2f((ushortT)(u4 & 0xffff)) + bf2f((ushortT)(u5 & 0xffff))
            + bf2f((ushortT)(u6 & 0xffff)) + bf2f((ushortT)(u7 & 0xffff));
        ay += bf2f((ushortT)(u0 >> 16)) + bf2f((ushortT)(u1 >> 16))
            + bf2f((ushortT)(u2 >> 16)) + bf2f((ushortT)(u3 >> 16))
            + bf2f((ushortT)(u4 >> 16)) + bf2f((ushortT)(u5 >> 16))
            + bf2f((ushortT)(u6 >> 16)) + bf2f((ushortT)(u7 >> 16));
    }
    unsigned int o = ((unsigned int)f2bf(ay) << 16) | (unsigned int)f2bf(ax);
    *(unsigned int*)&T[(size_t)gid * 128 + lane * 2] = o;
}

// ======== FUSED DOUBLE-GEMM: C = relu(relu(A@W1+add1)@W2+add2), per-wave 32 rows,
// ======== H via wave-private LDS window (no barriers); A from global, B from L1-resident W.
__global__ __launch_bounds__(256) void k_gemm_f(const ushortT* __restrict__ A,
                                                const ushortT* __restrict__ W1, const float* __restrict__ add1,
                                                const ushortT* __restrict__ W2, const float* __restrict__ add2,
                                                ushortT* __restrict__ C) {
    __shared__ ushortT tile[128 * 136];      // 4 waves x 32 rows, stride 136 (2-way alias only)
    int tid = threadIdx.x;
    int wave = tid >> 6, lane = tid & 63;
    int quad = lane >> 4, l16 = lane & 15;
    int base = blockIdx.x * 128 + wave * 32;
    ushortT* wt = tile + (wave * 32) * 136;

    f32x4 acc[2][8];
#pragma unroll
    for (int t2 = 0; t2 < 2; ++t2)
#pragma unroll
        for (int c = 0; c < 8; ++c) acc[t2][c] = (f32x4){0.f, 0.f, 0.f, 0.f};

    bf16x8 af[2][4];
#pragma unroll
    for (int t2 = 0; t2 < 2; ++t2)
#pragma unroll
        for (int kc = 0; kc < 4; ++kc)
            af[t2][kc] = *(const bf16x8*)&A[(size_t)(base + t2 * 16 + l16) * 128 + kc * 32 + quad * 8];

#pragma unroll
    for (int kc = 0; kc < 4; ++kc) {
#pragma unroll
        for (int c = 0; c < 8; ++c) {
            bf16x8 b1 = *(const bf16x8*)&W1[(c * 16 + l16) * 128 + kc * 32 + quad * 8];
            acc[0][c] = __builtin_amdgcn_mfma_f32_16x16x32_bf16(af[0][kc], b1, acc[0][c], 0, 0, 0);
            acc[1][c] = __builtin_amdgcn_mfma_f32_16x16x32_bf16(af[1][kc], b1, acc[1][c], 0, 0, 0);
        }
    }

    // H = relu(acc + add1) -> wave-private LDS window
#pragma unroll
    for (int t2 = 0; t2 < 2; ++t2) {
#pragma unroll
        for (int c = 0; c < 8; ++c) {
            int n = c * 16 + l16;
            float ad = add1[n];
#pragma unroll
            for (int r = 0; r < 4; ++r) {
                float y = acc[t2][c][r] + ad;
                y = y > 0.f ? y : 0.f;
                wt[(t2 * 16 + quad * 4 + r) * 136 + n] = f2bf(y);
            }
        }
    }

    // gemm2
#pragma unroll
    for (int t2 = 0; t2 < 2; ++t2)
#pragma unroll
        for (int c = 0; c < 8; ++c) acc[t2][c] = (f32x4){0.f, 0.f, 0.f, 0.f};
#pragma unroll
    for (int t2 = 0; t2 < 2; ++t2)
#pragma unroll
        for (int kc = 0; kc < 4; ++kc)
            af[t2][kc] = *(const bf16x8*)&wt[(t2 * 16 + l16) * 136 + kc * 32 + quad * 8];
#pragma unroll
    for (int kc = 0; kc < 4; ++kc) {
#pragma unroll
        for (int c = 0; c < 8; ++c) {
            bf16x8 b2 = *(const bf16x8*)&W2[(c * 16 + l16) * 128 + kc * 32 + quad * 8];
            acc[0][c] = __builtin_amdgcn_mfma_f32_16x16x32_bf16(af[0][kc], b2, acc[0][c], 0, 0, 0);
            acc[1][c] = __builtin_amdgcn_mfma_f32_16x16x32_bf16(af[1][kc], b2, acc[1][c], 0, 0, 0);
        }
    }

    // epilogue: C = relu(acc + add2)
#pragma unroll
    for (int t2 = 0; t2 < 2; ++t2) {
#pragma unroll
        for (int c = 0; c < 8; ++c) {
            int n = c * 16 + l16;
            float ad = add2[n];
#pragma unroll
            for (int r = 0; r < 4; ++r) {
                int row = base + t2 * 16 + quad * 4 + r;
                if (row < N_NODES) {
                    float y = acc[t2][c][r] + ad;
                    y = y > 0.f ? y : 0.f;
                    C[(size_t)row * 128 + n] = f2bf(y);
                }
            }
        }
    }
}

// ------- pooling: wave-per-row-slice run-length accumulation, unroll-4 -------
#define POOL_CHUNK 512
__global__ __launch_bounds__(256) void k_pool(const ushortT* __restrict__ H, const int* __restrict__ batch,
                                              float* __restrict__ P, int off) {
    int n0 = blockIdx.x * POOL_CHUNK;
    int lane = threadIdx.x & 63;
    int s = threadIdx.x >> 6;                // 4 interleaved node streams (one per wave)
    int d2 = lane * 2;                       // two dims per thread
    int end = n0 + POOL_CHUNK;
    if (end > N_NODES) end = N_NODES;
    float ax = 0.f, ay = 0.f;
    int cur = -1;
    int i = n0 + s;
    for (; i + 12 < end; i += 16) {
        int g0 = batch[i], g1 = batch[i + 4], g2 = batch[i + 8], g3 = batch[i + 12];
        unsigned int u0 = *(const unsigned int*)&H[(size_t)i * 128 + d2];
        unsigned int u1 = *(const unsigned int*)&H[(size_t)(i + 4) * 128 + d2];
        unsigned int u2 = *(const unsigned int*)&H[(size_t)(i + 8) * 128 + d2];
        unsigned int u3 = *(const unsigned int*)&H[(size_t)(i + 12) * 128 + d2];
        int gs[4] = {g0, g1, g2, g3};
        unsigned int us[4] = {u0, u1, u2, u3};
#pragma unroll
        for (int q = 0; q < 4; ++q) {
            if (gs[q] != cur) {
                if (cur >= 0) {
                    atomicAdd(&P[cur * 384 + off + d2], ax);
                    atomicAdd(&P[cur * 384 + off + d2 + 1], ay);
                }
                cur = gs[q];
                ax = 0.f; ay = 0.f;
            }
            ax += bf2f((ushortT)(us[q] & 0xffff));
            ay += bf2f((ushortT)(us[q] >> 16));
        }
    }
    for (; i < end; i += 4) {
        int gi = batch[i];
        unsigned int u = *(const unsigned int*)&H[(size_t)i * 128 + d2];
        if (gi != cur) {
            if (cur >= 0) {
                atomicAdd(&P[cur * 384 + off + d2], ax);
                atomicAdd(&P[cur * 384 + off + d2 + 1], ay);
            }
            cur = gi;
            ax = 0.f; ay = 0.f;
        }
        ax += bf2f((ushortT)(u & 0xffff));
        ay += bf2f((ushortT)(u >> 16));
    }
    if (cur >= 0) {
        atomicAdd(&P[cur * 384 + off + d2], ax);
        atomicAdd(&P[cur * 384 + off + d2 + 1], ay);
    }
}

// ---------------- head: out = relu(P @ W1 + b1) @ W2 + b2  (all fp32) ------------
__global__ __launch_bounds__(384) void k_head(const float* __restrict__ P, const float* __restrict__ W1,
                                              const float* __restrict__ B1, const float* __restrict__ W2,
                                              const float* __restrict__ B2, float* __restrict__ out) {
    __shared__ float pr[384];
    __shared__ float qr[384];
    int g = blockIdx.x, t = threadIdx.x;
    pr[t] = P[g * 384 + t];
    __syncthreads();
    float a = 0.f;
    for (int k = 0; k < 384; ++k) a += pr[k] * W1[k * 384 + t];
    a += B1[t];
    qr[t] = a > 0.f ? a : 0.f;
    __syncthreads();
    if (t < 10) {
        float o = 0.f;
        for (int k = 0; k < 384; ++k) o += qr[k] * W2[k * 10 + t];
        o += B2[t];
        out[g * 10 + t] = o;
    }
}

extern "C" void kernel_launch(void* const* d_in, const int* in_sizes, int n_in,
                              void* d_out, int out_size, void* d_ws, size_t ws_size,
                              hipStream_t stream) {
    const float* x     = (const float*)d_in[0];
    const int*   ei    = (const int*)d_in[1];
    const int*   srcA  = ei;
    const int*   dstA  = ei + N_EDGES;
    const int*   batch = (const int*)d_in[2];
    const float* c1_w1 = (const float*)d_in[3];
    const float* c1_b1 = (const float*)d_in[4];
    const float* c1_g  = (const float*)d_in[5];
    const float* c1_be = (const float*)d_in[6];
    const float* c1_w2 = (const float*)d_in[7];
    const float* c1_b2 = (const float*)d_in[8];
    const float* c2_w1 = (const float*)d_in[9];
    const float* c2_b1 = (const float*)d_in[10];
    const float* c2_g  = (const float*)d_in[11];
    const float* c2_be = (const float*)d_in[12];
    const float* c2_w2 = (const float*)d_in[13];
    const float* c2_b2 = (const float*)d_in[14];
    const float* c3_w1 = (const float*)d_in[15];
    const float* c3_b1 = (const float*)d_in[16];
    const float* c3_g  = (const float*)d_in[17];
    const float* c3_be = (const float*)d_in[18];
    const float* c3_w2 = (const float*)d_in[19];
    const float* c3_b2 = (const float*)d_in[20];
    const float* l1w   = (const float*)d_in[21];
    const float* l1b   = (const float*)d_in[22];
    const float* l2w   = (const float*)d_in[23];
    const float* l2b   = (const float*)d_in[24];
    float* out = (float*)d_out;

    size_t o = 0;
    char* base = (char*)d_ws;
    auto alloc = [&](size_t n) -> char* {
        char* p = base + o;
        o += (n + 255) & ~(size_t)255;
        return p;
    };
    ushortT* Wt    = (ushortT*)alloc(6 * 16384 * 2);
    float*   addv  = (float*)alloc(6 * 128 * 4);
    int*     deg   = (int*)alloc((size_t)N_NODES * 4);
    int*     gcur  = (int*)alloc((size_t)NBUCK * 4);
    int*     tscan = (int*)alloc((size_t)100352 * 4);
    int*     bsum  = (int*)alloc(98 * 4);
    int*     boff  = (int*)alloc(98 * 4);
    int*     pst   = (int*)alloc((size_t)(N_NODES + 1) * 4);
    int*     colA  = (int*)alloc((size_t)COL_CAP * 4);
    ushortT* bufA  = (ushortT*)alloc((size_t)MPAD * 128 * 2);   // agg out; ebin aliases this
    ushortT* bufB  = (ushortT*)alloc((size_t)MPAD * 128 * 2);   // L0/L2 out
    ushortT* bufC  = (ushortT*)alloc((size_t)MPAD * 128 * 2);   // x(bf16) / L1 out
    float*   pbuf  = (float*)alloc((size_t)N_GRAPHS * 384 * 4);
    int2*    ebin  = (int2*)bufA;   // 782*3072*8 = 19.2 MB <= 25.6 MB; dead before first k_agg

    hipMemsetAsync(gcur, 0, (size_t)NBUCK * 4, stream);
    hipMemsetAsync(pbuf, 0, (size_t)N_GRAPHS * 384 * 4, stream);
    // gather pad row (index N_NODES) must be zero in bufB (used as gather input in L1)
    hipMemsetAsync(bufB + (size_t)N_NODES * 128, 0, 256, stream);

    k_prep<<<386, 256, 0, stream>>>(c1_w1, c1_w2, c2_w1, c2_w2, c3_w1, c3_w2,
                                    c1_b1, c1_g, c1_be, c1_b2,
                                    c2_b1, c2_g, c2_be, c2_b2,
                                    c3_b1, c3_g, c3_be, c3_b2,
                                    Wt, addv);
    k_cvt<<<(MPAD * 128 / 4 + 255) / 256, 256, 0, stream>>>(x, bufC);
    kb_scatter<<<256, 256, 0, stream>>>(srcA, dstA, gcur, ebin);
    kb_count<<<NBUCK, 256, 0, stream>>>(ebin, gcur, deg);
    k_scan1<<<98, 1024, 0, stream>>>(deg, tscan, bsum);
    k_scan2<<<1, 64, 0, stream>>>(bsum, boff);
    k_scan3<<<391, 256, 0, stream>>>(tscan, boff, pst);
    kb_fill<<<NBUCK, 256, 0, stream>>>(ebin, gcur, pst, colA);
    k_padfill<<<391, 256, 0, stream>>>(deg, pst, colA);

    // L0: bufC -> (agg) bufA -> (2xgemm) bufB ; L1: bufB -> bufA -> bufC ; L2: bufC -> bufA -> bufB
    k_agg<<<MPAD / 4, 256, 0, stream>>>(bufC, pst, colA, bufA);
    k_gemm_f<<<MPAD / 128, 256, 0, stream>>>(bufA, Wt + 0 * 16384, addv + 0 * 128,
                                             Wt + 1 * 16384, addv + 1 * 128, bufB);
    k_pool<<<(N_NODES + POOL_CHUNK - 1) / POOL_CHUNK, 256, 0, stream>>>(bufB, batch, pbuf, 0);
    k_agg<<<MPAD / 4, 256, 0, stream>>>(bufB, pst, colA, bufA);
    k_gemm_f<<<MPAD / 128, 256, 0, stream>>>(bufA, Wt + 2 * 16384, addv + 2 * 128,
                                             Wt + 3 * 16384, addv + 3 * 128, bufC);
    k_pool<<<(N_NODES + POOL_CHUNK - 1) / POOL_CHUNK, 256, 0, stream>>>(bufC, batch, pbuf, 128);
    k_agg<<<MPAD / 4, 256, 0, stream>>>(bufC, pst, colA, bufA);
    k_gemm_f<<<MPAD / 128, 256, 0, stream>>>(bufA, Wt + 4 * 16384, addv + 4 * 128,
                                             Wt + 5 * 16384, addv + 5 * 128, bufB);
    k_pool<<<(N_NODES + POOL_CHUNK - 1) / POOL_CHUNK, 256, 0, stream>>>(bufB, batch, pbuf, 256);

    k_head<<<N_GRAPHS, 384, 0, stream>>>(pbuf, l1w, l1b, l2w, l2b, out);
}

// Round 8
// 573.832 us; speedup vs baseline: 1.4453x; 1.1291x over previous
//
#include <hip/hip_runtime.h>

#define N_NODES 100000
#define N_EDGES 1600000
#define N_GRAPHS 512
#define MPAD 100096      // 782 * 128 (also 1564 * 64)
#define COL_CAP 2400000  // N_EDGES + 8*N_NODES worst case
#define NBUCK 782        // buckets of 128 nodes (dst >> 7)
#define BCAP 3072        // per-bucket capacity; mean 2046, sigma ~45 -> 22 sigma margin

typedef unsigned short ushortT;
typedef __attribute__((ext_vector_type(8))) short bf16x8;
typedef __attribute__((ext_vector_type(4))) float f32x4;
typedef __attribute__((ext_vector_type(4))) unsigned int uint4v;

__device__ inline float bf2f(ushortT u) {
    unsigned int x = ((unsigned int)u) << 16;
    return __builtin_bit_cast(float, x);
}
__device__ inline ushortT f2bf(float f) {
    unsigned int x = __builtin_bit_cast(unsigned int, f);
    unsigned int r = (x + 0x7fffu + ((x >> 16) & 1u)) >> 16;
    return (ushortT)r;
}

// ---------------- prep: transpose fp32 weights -> bf16 Wt (fold BN scale), build add vectors ----
__global__ __launch_bounds__(256) void k_prep(
    const float* __restrict__ w11, const float* __restrict__ w12,
    const float* __restrict__ w21, const float* __restrict__ w22,
    const float* __restrict__ w31, const float* __restrict__ w32,
    const float* __restrict__ b11, const float* __restrict__ g1, const float* __restrict__ be1, const float* __restrict__ b12,
    const float* __restrict__ b21, const float* __restrict__ g2, const float* __restrict__ be2, const float* __restrict__ b22,
    const float* __restrict__ b31, const float* __restrict__ g3, const float* __restrict__ be3, const float* __restrict__ b32,
    ushortT* __restrict__ Wt, float* __restrict__ addv)
{
    int bid = blockIdx.x, t = threadIdx.x;
    const float rs = rsqrtf(1.0f + 1e-5f);
    if (bid < 384) {
        int idx = bid * 256 + t;             // 0..98303
        int m = idx >> 14;                   // matrix 0..5
        int r = idx & 16383;
        int k = r & 127;
        int n = r >> 7;
        const float* W = (m == 0) ? w11 : (m == 1) ? w12 : (m == 2) ? w21
                       : (m == 3) ? w22 : (m == 4) ? w31 : w32;
        float v = W[k * 128 + n];
        if ((m & 1) == 0) {                  // a "w1": fold BN scale per out-col n
            const float* gm = (m == 0) ? g1 : (m == 2) ? g2 : g3;
            v *= gm[n] * rs;
        }
        Wt[m * 16384 + n * 128 + k] = f2bf(v);
    } else if (bid == 384) {                 // gemm1 adds: b1*s + beta
        if (t < 384) {
            int L = t >> 7, n = t & 127;
            const float* bb = (L == 0) ? b11 : (L == 1) ? b21 : b31;
            const float* gm = (L == 0) ? g1 : (L == 1) ? g2 : g3;
            const float* be = (L == 0) ? be1 : (L == 1) ? be2 : be3;
            float s = gm[n] * rs;
            addv[(2 * L) * 128 + n] = bb[n] * s + be[n];
        }
    } else {                                 // gemm2 adds: b2
        if (t < 384) {
            int L = t >> 7, n = t & 127;
            const float* bb = (L == 0) ? b12 : (L == 1) ? b22 : b32;
            addv[(2 * L + 1) * 128 + n] = bb[n];
        }
    }
}

// ---------------- x (fp32) -> bf16, plus zeroed padding rows ----------------
__global__ __launch_bounds__(256) void k_cvt(const float* __restrict__ X, ushortT* __restrict__ Y) {
    size_t i = ((size_t)blockIdx.x * 256 + threadIdx.x) * 4;
    if (i >= (size_t)MPAD * 128) return;
    unsigned long long o = 0ull;
    if (i < (size_t)N_NODES * 128) {
        float4 v = *(const float4*)&X[i];
        o = (unsigned long long)f2bf(v.x)
          | ((unsigned long long)f2bf(v.y) << 16)
          | ((unsigned long long)f2bf(v.z) << 32)
          | ((unsigned long long)f2bf(v.w) << 48);
    }
    *(unsigned long long*)&Y[i] = o;
}

// ------- bucket binning: scatter (src,dst) into dst-range buckets, L2-local writes -------
__global__ __launch_bounds__(256) void kb_scatter(const int* __restrict__ src, const int* __restrict__ dst,
                                                  int* __restrict__ gcur, int2* __restrict__ ebin) {
    __shared__ int lcnt[NBUCK];
    __shared__ int lbase[NBUCK];
    int t = threadIdx.x;
    int e0 = blockIdx.x * (N_EDGES / 256);
    int e1 = e0 + (N_EDGES / 256);
    for (int i = t; i < NBUCK; i += 256) lcnt[i] = 0;
    __syncthreads();
    for (int e = e0 + t; e < e1; e += 256) atomicAdd(&lcnt[dst[e] >> 7], 1);
    __syncthreads();
    for (int i = t; i < NBUCK; i += 256) {
        int c = lcnt[i];
        lbase[i] = c ? atomicAdd(&gcur[i], c) : 0;
    }
    __syncthreads();
    for (int i = t; i < NBUCK; i += 256) lcnt[i] = 0;
    __syncthreads();
    for (int e = e0 + t; e < e1; e += 256) {
        int d = dst[e];
        int b = d >> 7;
        int off = atomicAdd(&lcnt[b], 1);
        ebin[(size_t)b * BCAP + lbase[b] + off] = make_int2(src[e], d);
    }
}

// ------- per-bucket degree count: LDS histogram, no global atomics -------
__global__ __launch_bounds__(256) void kb_count(const int2* __restrict__ ebin, const int* __restrict__ gcur,
                                                int* __restrict__ deg) {
    __shared__ int cnt[128];
    int b = blockIdx.x, t = threadIdx.x;
    if (t < 128) cnt[t] = 0;
    __syncthreads();
    int m = gcur[b];
    const int2* eb = ebin + (size_t)b * BCAP;
    for (int e = t; e < m; e += 256) atomicAdd(&cnt[eb[e].y & 127], 1);
    __syncthreads();
    if (t < 128) {
        int node = b * 128 + t;
        if (node < N_NODES) deg[node] = cnt[t];
    }
}

__global__ __launch_bounds__(1024) void k_scan1(const int* __restrict__ deg, int* __restrict__ tscan,
                                                int* __restrict__ bsum) {
    __shared__ int s[1024];
    int t = threadIdx.x;
    int i = blockIdx.x * 1024 + t;
    int v = (i < N_NODES) ? ((deg[i] + 7) & ~7) : 0;   // padded degree
    s[t] = v;
    __syncthreads();
    for (int off = 1; off < 1024; off <<= 1) {
        int tmp = (t >= off) ? s[t - off] : 0;
        __syncthreads();
        s[t] += tmp;
        __syncthreads();
    }
    tscan[i] = s[t];
    if (t == 1023) bsum[blockIdx.x] = s[1023];
}

__global__ void k_scan2(const int* __restrict__ bsum, int* __restrict__ boff) {
    if (threadIdx.x == 0 && blockIdx.x == 0) {
        int run = 0;
        for (int b = 0; b < 98; ++b) { boff[b] = run; run += bsum[b]; }
    }
}

__global__ __launch_bounds__(256) void k_scan3(const int* __restrict__ tscan, const int* __restrict__ boff,
                                               int* __restrict__ pstart) {
    int i = blockIdx.x * 256 + threadIdx.x;
    if (i > N_NODES) return;
    pstart[i] = (i == 0) ? 0 : tscan[i - 1] + boff[(i - 1) >> 10];
}

// ------- per-bucket CSR fill: LDS cursors, writes confined to bucket's CSR window -------
__global__ __launch_bounds__(256) void kb_fill(const int2* __restrict__ ebin, const int* __restrict__ gcur,
                                               const int* __restrict__ pstart, int* __restrict__ col) {
    __shared__ int ps[128];
    __shared__ int cur[128];
    int b = blockIdx.x, t = threadIdx.x;
    if (t < 128) {
        int node = b * 128 + t;
        ps[t] = (node < N_NODES) ? pstart[node] : 0;
        cur[t] = 0;
    }
    __syncthreads();
    int m = gcur[b];
    const int2* eb = ebin + (size_t)b * BCAP;
    for (int e = t; e < m; e += 256) {
        int2 sd = eb[e];
        int idx = sd.y & 127;
        int pos = ps[idx] + atomicAdd(&cur[idx], 1);
        col[pos] = sd.x;
    }
}

// pad each node's list up to multiple of 8 with index N_NODES (a guaranteed-zero row)
__global__ __launch_bounds__(256) void k_padfill(const int* __restrict__ deg, const int* __restrict__ pstart,
                                                 int* __restrict__ col) {
    int i = blockIdx.x * 256 + threadIdx.x;
    if (i >= N_NODES) return;
    int s = pstart[i] + deg[i];
    int e = pstart[i + 1];
    for (int j = s; j < e; ++j) col[j] = N_NODES;
}

// ------- aggregation (bf16): T[i] = bf16(X[i] + sum_j X[col[j]]), unroll-8 branch-free -------
__global__ __launch_bounds__(256) void k_agg(const ushortT* __restrict__ X, const int* __restrict__ pstart,
                                             const int* __restrict__ col, ushortT* __restrict__ T) {
    int gid = blockIdx.x * 4 + (threadIdx.x >> 6);
    int lane = threadIdx.x & 63;
    if (gid >= MPAD) return;
    if (gid >= N_NODES) {                    // zero padding rows (MFMA A-operand hygiene)
        *(unsigned int*)&T[(size_t)gid * 128 + lane * 2] = 0u;
        return;
    }
    int lo = pstart[gid], hi = pstart[gid + 1];
    unsigned int v = *(const unsigned int*)&X[(size_t)gid * 128 + lane * 2];
    float ax = bf2f((ushortT)(v & 0xffff));
    float ay = bf2f((ushortT)(v >> 16));
    for (int j = lo; j < hi; j += 8) {       // (hi-lo) % 8 == 0 by construction
        int4 c0 = *(const int4*)&col[j];
        int4 c1 = *(const int4*)&col[j + 4];
        unsigned int u0 = *(const unsigned int*)&X[(size_t)c0.x * 128 + lane * 2];
        unsigned int u1 = *(const unsigned int*)&X[(size_t)c0.y * 128 + lane * 2];
        unsigned int u2 = *(const unsigned int*)&X[(size_t)c0.z * 128 + lane * 2];
        unsigned int u3 = *(const unsigned int*)&X[(size_t)c0.w * 128 + lane * 2];
        unsigned int u4 = *(const unsigned int*)&X[(size_t)c1.x * 128 + lane * 2];
        unsigned int u5 = *(const unsigned int*)&X[(size_t)c1.y * 128 + lane * 2];
        unsigned int u6 = *(const unsigned int*)&X[(size_t)c1.z * 128 + lane * 2];
        unsigned int u7 = *(const unsigned int*)&X[(size_t)c1.w * 128 + lane * 2];
        ax += bf2f((ushortT)(u0 & 0xffff)) + bf2f((ushortT)(u1 & 0xffff))
            + bf2f((ushortT)(u2 & 0xffff)) + bf2f((ushortT)(u3 & 0xffff))
            + bf2f((ushortT)(u4 & 0xffff)) + bf2f((ushortT)(u5 & 0xffff))
            + bf2f((ushortT)(u6 & 0xffff)) + bf2f((ushortT)(u7 & 0xffff));
        ay += bf2f((ushortT)(u0 >> 16)) + bf2f((ushortT)(u1 >> 16))
            + bf2f((ushortT)(u2 >> 16)) + bf2f((ushortT)(u3 >> 16))
            + bf2f((ushortT)(u4 >> 16)) + bf2f((ushortT)(u5 >> 16))
            + bf2f((ushortT)(u6 >> 16)) + bf2f((ushortT)(u7 >> 16));
    }
    unsigned int o = ((unsigned int)f2bf(ay) << 16) | (unsigned int)f2bf(ax);
    *(unsigned int*)&T[(size_t)gid * 128 + lane * 2] = o;
}

// ======== FUSED DOUBLE-GEMM, LDS-staged B: C = relu(relu(A@W1+add1)@W2+add2).
// 64 rows/block, 4 waves x 16 rows. LDS: W region (34.8KB, W1 then W2) + H tile (17.4KB).
__global__ __launch_bounds__(256) void k_gemm_f(const ushortT* __restrict__ A,
                                                const ushortT* __restrict__ W1, const float* __restrict__ add1,
                                                const ushortT* __restrict__ W2, const float* __restrict__ add2,
                                                ushortT* __restrict__ C) {
    __shared__ ushortT wlds[128 * 136];      // staged weights (reused: W1 -> W2)
    __shared__ ushortT hlds[64 * 136];       // H tile, wave-private 16-row windows
    int tid = threadIdx.x;
    int wave = tid >> 6, lane = tid & 63;
    int quad = lane >> 4, l16 = lane & 15;
    int base = blockIdx.x * 64 + wave * 16;

    // A-fragments from global first (overlaps W1 staging)
    bf16x8 af[4];
#pragma unroll
    for (int kc = 0; kc < 4; ++kc)
        af[kc] = *(const bf16x8*)&A[(size_t)(base + l16) * 128 + kc * 32 + quad * 8];

    // stage W1
#pragma unroll
    for (int it = 0; it < 8; ++it) {
        int idx = (it * 256 + tid) * 8;
        int n = idx >> 7, k = idx & 127;
        *(uint4v*)&wlds[n * 136 + k] = *(const uint4v*)&W1[idx];
    }
    __syncthreads();

    // gemm1
    f32x4 acc[8];
#pragma unroll
    for (int c = 0; c < 8; ++c) acc[c] = (f32x4){0.f, 0.f, 0.f, 0.f};
#pragma unroll
    for (int kc = 0; kc < 4; ++kc) {
#pragma unroll
        for (int c = 0; c < 8; ++c) {
            bf16x8 b1 = *(const bf16x8*)&wlds[(c * 16 + l16) * 136 + kc * 32 + quad * 8];
            acc[c] = __builtin_amdgcn_mfma_f32_16x16x32_bf16(af[kc], b1, acc[c], 0, 0, 0);
        }
    }
    __syncthreads();                         // all waves done reading W1

    // stage W2 over W1's region, and write H into wave-private tile
#pragma unroll
    for (int it = 0; it < 8; ++it) {
        int idx = (it * 256 + tid) * 8;
        int n = idx >> 7, k = idx & 127;
        *(uint4v*)&wlds[n * 136 + k] = *(const uint4v*)&W2[idx];
    }
    ushortT* hw = hlds + (wave * 16) * 136;
#pragma unroll
    for (int c = 0; c < 8; ++c) {
        int n = c * 16 + l16;
        float ad = add1[n];
#pragma unroll
        for (int r = 0; r < 4; ++r) {
            float y = acc[c][r] + ad;
            y = y > 0.f ? y : 0.f;
            hw[(quad * 4 + r) * 136 + n] = f2bf(y);
        }
    }
    __syncthreads();                         // W2 staged (H is wave-local)

    // gemm2
#pragma unroll
    for (int c = 0; c < 8; ++c) acc[c] = (f32x4){0.f, 0.f, 0.f, 0.f};
#pragma unroll
    for (int kc = 0; kc < 4; ++kc)
        af[kc] = *(const bf16x8*)&hw[l16 * 136 + kc * 32 + quad * 8];
#pragma unroll
    for (int kc = 0; kc < 4; ++kc) {
#pragma unroll
        for (int c = 0; c < 8; ++c) {
            bf16x8 b2 = *(const bf16x8*)&wlds[(c * 16 + l16) * 136 + kc * 32 + quad * 8];
            acc[c] = __builtin_amdgcn_mfma_f32_16x16x32_bf16(af[kc], b2, acc[c], 0, 0, 0);
        }
    }

    // epilogue: C = relu(acc + add2)
#pragma unroll
    for (int c = 0; c < 8; ++c) {
        int n = c * 16 + l16;
        float ad = add2[n];
#pragma unroll
        for (int r = 0; r < 4; ++r) {
            int row = base + quad * 4 + r;
            if (row < N_NODES) {
                float y = acc[c][r] + ad;
                y = y > 0.f ? y : 0.f;
                C[(size_t)row * 128 + n] = f2bf(y);
            }
        }
    }
}

// ------- pooling: wave-per-row-slice run-length accumulation, unroll-4 -------
#define POOL_CHUNK 512
__global__ __launch_bounds__(256) void k_pool(const ushortT* __restrict__ H, const int* __restrict__ batch,
                                              float* __restrict__ P, int off) {
    int n0 = blockIdx.x * POOL_CHUNK;
    int lane = threadIdx.x & 63;
    int s = threadIdx.x >> 6;                // 4 interleaved node streams (one per wave)
    int d2 = lane * 2;                       // two dims per thread
    int end = n0 + POOL_CHUNK;
    if (end > N_NODES) end = N_NODES;
    float ax = 0.f, ay = 0.f;
    int cur = -1;
    int i = n0 + s;
    for (; i + 12 < end; i += 16) {
        int g0 = batch[i], g1 = batch[i + 4], g2 = batch[i + 8], g3 = batch[i + 12];
        unsigned int u0 = *(const unsigned int*)&H[(size_t)i * 128 + d2];
        unsigned int u1 = *(const unsigned int*)&H[(size_t)(i + 4) * 128 + d2];
        unsigned int u2 = *(const unsigned int*)&H[(size_t)(i + 8) * 128 + d2];
        unsigned int u3 = *(const unsigned int*)&H[(size_t)(i + 12) * 128 + d2];
        int gs[4] = {g0, g1, g2, g3};
        unsigned int us[4] = {u0, u1, u2, u3};
#pragma unroll
        for (int q = 0; q < 4; ++q) {
            if (gs[q] != cur) {
                if (cur >= 0) {
                    atomicAdd(&P[cur * 384 + off + d2], ax);
                    atomicAdd(&P[cur * 384 + off + d2 + 1], ay);
                }
                cur = gs[q];
                ax = 0.f; ay = 0.f;
            }
            ax += bf2f((ushortT)(us[q] & 0xffff));
            ay += bf2f((ushortT)(us[q] >> 16));
        }
    }
    for (; i < end; i += 4) {
        int gi = batch[i];
        unsigned int u = *(const unsigned int*)&H[(size_t)i * 128 + d2];
        if (gi != cur) {
            if (cur >= 0) {
                atomicAdd(&P[cur * 384 + off + d2], ax);
                atomicAdd(&P[cur * 384 + off + d2 + 1], ay);
            }
            cur = gi;
            ax = 0.f; ay = 0.f;
        }
        ax += bf2f((ushortT)(u & 0xffff));
        ay += bf2f((ushortT)(u >> 16));
    }
    if (cur >= 0) {
        atomicAdd(&P[cur * 384 + off + d2], ax);
        atomicAdd(&P[cur * 384 + off + d2 + 1], ay);
    }
}

// ---------------- head: out = relu(P @ W1 + b1) @ W2 + b2  (all fp32) ------------
__global__ __launch_bounds__(384) void k_head(const float* __restrict__ P, const float* __restrict__ W1,
                                              const float* __restrict__ B1, const float* __restrict__ W2,
                                              const float* __restrict__ B2, float* __restrict__ out) {
    __shared__ float pr[384];
    __shared__ float qr[384];
    int g = blockIdx.x, t = threadIdx.x;
    pr[t] = P[g * 384 + t];
    __syncthreads();
    float a = 0.f;
    for (int k = 0; k < 384; ++k) a += pr[k] * W1[k * 384 + t];
    a += B1[t];
    qr[t] = a > 0.f ? a : 0.f;
    __syncthreads();
    if (t < 10) {
        float o = 0.f;
        for (int k = 0; k < 384; ++k) o += qr[k] * W2[k * 10 + t];
        o += B2[t];
        out[g * 10 + t] = o;
    }
}

extern "C" void kernel_launch(void* const* d_in, const int* in_sizes, int n_in,
                              void* d_out, int out_size, void* d_ws, size_t ws_size,
                              hipStream_t stream) {
    const float* x     = (const float*)d_in[0];
    const int*   ei    = (const int*)d_in[1];
    const int*   srcA  = ei;
    const int*   dstA  = ei + N_EDGES;
    const int*   batch = (const int*)d_in[2];
    const float* c1_w1 = (const float*)d_in[3];
    const float* c1_b1 = (const float*)d_in[4];
    const float* c1_g  = (const float*)d_in[5];
    const float* c1_be = (const float*)d_in[6];
    const float* c1_w2 = (const float*)d_in[7];
    const float* c1_b2 = (const float*)d_in[8];
    const float* c2_w1 = (const float*)d_in[9];
    const float* c2_b1 = (const float*)d_in[10];
    const float* c2_g  = (const float*)d_in[11];
    const float* c2_be = (const float*)d_in[12];
    const float* c2_w2 = (const float*)d_in[13];
    const float* c2_b2 = (const float*)d_in[14];
    const float* c3_w1 = (const float*)d_in[15];
    const float* c3_b1 = (const float*)d_in[16];
    const float* c3_g  = (const float*)d_in[17];
    const float* c3_be = (const float*)d_in[18];
    const float* c3_w2 = (const float*)d_in[19];
    const float* c3_b2 = (const float*)d_in[20];
    const float* l1w   = (const float*)d_in[21];
    const float* l1b   = (const float*)d_in[22];
    const float* l2w   = (const float*)d_in[23];
    const float* l2b   = (const float*)d_in[24];
    float* out = (float*)d_out;

    size_t o = 0;
    char* base = (char*)d_ws;
    auto alloc = [&](size_t n) -> char* {
        char* p = base + o;
        o += (n + 255) & ~(size_t)255;
        return p;
    };
    ushortT* Wt    = (ushortT*)alloc(6 * 16384 * 2);
    float*   addv  = (float*)alloc(6 * 128 * 4);
    int*     deg   = (int*)alloc((size_t)N_NODES * 4);
    int*     gcur  = (int*)alloc((size_t)NBUCK * 4);
    int*     tscan = (int*)alloc((size_t)100352 * 4);
    int*     bsum  = (int*)alloc(98 * 4);
    int*     boff  = (int*)alloc(98 * 4);
    int*     pst   = (int*)alloc((size_t)(N_NODES + 1) * 4);
    int*     colA  = (int*)alloc((size_t)COL_CAP * 4);
    ushortT* bufA  = (ushortT*)alloc((size_t)MPAD * 128 * 2);   // agg out; ebin aliases this
    ushortT* bufB  = (ushortT*)alloc((size_t)MPAD * 128 * 2);   // L0/L2 out
    ushortT* bufC  = (ushortT*)alloc((size_t)MPAD * 128 * 2);   // x(bf16) / L1 out
    float*   pbuf  = (float*)alloc((size_t)N_GRAPHS * 384 * 4);
    int2*    ebin  = (int2*)bufA;   // 782*3072*8 = 19.2 MB <= 25.6 MB; dead before first k_agg

    hipMemsetAsync(gcur, 0, (size_t)NBUCK * 4, stream);
    hipMemsetAsync(pbuf, 0, (size_t)N_GRAPHS * 384 * 4, stream);
    // gather pad row (index N_NODES) must be zero in bufB (used as gather input in L1)
    hipMemsetAsync(bufB + (size_t)N_NODES * 128, 0, 256, stream);

    k_prep<<<386, 256, 0, stream>>>(c1_w1, c1_w2, c2_w1, c2_w2, c3_w1, c3_w2,
                                    c1_b1, c1_g, c1_be, c1_b2,
                                    c2_b1, c2_g, c2_be, c2_b2,
                                    c3_b1, c3_g, c3_be, c3_b2,
                                    Wt, addv);
    k_cvt<<<(MPAD * 128 / 4 + 255) / 256, 256, 0, stream>>>(x, bufC);
    kb_scatter<<<256, 256, 0, stream>>>(srcA, dstA, gcur, ebin);
    kb_count<<<NBUCK, 256, 0, stream>>>(ebin, gcur, deg);
    k_scan1<<<98, 1024, 0, stream>>>(deg, tscan, bsum);
    k_scan2<<<1, 64, 0, stream>>>(bsum, boff);
    k_scan3<<<391, 256, 0, stream>>>(tscan, boff, pst);
    kb_fill<<<NBUCK, 256, 0, stream>>>(ebin, gcur, pst, colA);
    k_padfill<<<391, 256, 0, stream>>>(deg, pst, colA);

    // L0: bufC -> (agg) bufA -> (fused 2xgemm) bufB ; L1: bufB -> bufA -> bufC ; L2: bufC -> bufA -> bufB
    k_agg<<<MPAD / 4, 256, 0, stream>>>(bufC, pst, colA, bufA);
    k_gemm_f<<<MPAD / 64, 256, 0, stream>>>(bufA, Wt + 0 * 16384, addv + 0 * 128,
                                            Wt + 1 * 16384, addv + 1 * 128, bufB);
    k_pool<<<(N_NODES + POOL_CHUNK - 1) / POOL_CHUNK, 256, 0, stream>>>(bufB, batch, pbuf, 0);
    k_agg<<<MPAD / 4, 256, 0, stream>>>(bufB, pst, colA, bufA);
    k_gemm_f<<<MPAD / 64, 256, 0, stream>>>(bufA, Wt + 2 * 16384, addv + 2 * 128,
                                            Wt + 3 * 16384, addv + 3 * 128, bufC);
    k_pool<<<(N_NODES + POOL_CHUNK - 1) / POOL_CHUNK, 256, 0, stream>>>(bufC, batch, pbuf, 128);
    k_agg<<<MPAD / 4, 256, 0, stream>>>(bufC, pst, colA, bufA);
    k_gemm_f<<<MPAD / 64, 256, 0, stream>>>(bufA, Wt + 4 * 16384, addv + 4 * 128,
                                            Wt + 5 * 16384, addv + 5 * 128, bufB);
    k_pool<<<(N_NODES + POOL_CHUNK - 1) / POOL_CHUNK, 256, 0, stream>>>(bufB, batch, pbuf, 256);

    k_head<<<N_GRAPHS, 384, 0, stream>>>(pbuf, l1w, l1b, l2w, l2b, out);
}

// Round 9
// 541.030 us; speedup vs baseline: 1.5330x; 1.0606x over previous
//
#include <hip/hip_runtime.h>

#define N_NODES 100000
#define N_EDGES 1600000
#define N_GRAPHS 512
#define MPAD 100096      // 782 * 128 (also 1564 * 64)
#define COL_CAP 2400000  // N_EDGES + 8*N_NODES worst case
#define NBUCK 782        // buckets of 128 nodes (dst >> 7)
#define BCAP 3072        // per-bucket capacity; mean 2046, sigma ~45 -> 22 sigma margin

typedef unsigned short ushortT;
typedef __attribute__((ext_vector_type(8))) short bf16x8;
typedef __attribute__((ext_vector_type(4))) float f32x4;
typedef __attribute__((ext_vector_type(4))) unsigned int uint4v;

__device__ inline float bf2f(ushortT u) {
    unsigned int x = ((unsigned int)u) << 16;
    return __builtin_bit_cast(float, x);
}
__device__ inline ushortT f2bf(float f) {
    unsigned int x = __builtin_bit_cast(unsigned int, f);
    unsigned int r = (x + 0x7fffu + ((x >> 16) & 1u)) >> 16;
    return (ushortT)r;
}

// ---------------- prep: transpose fp32 weights -> bf16 Wt (fold BN scale), build add vectors ----
__global__ __launch_bounds__(256) void k_prep(
    const float* __restrict__ w11, const float* __restrict__ w12,
    const float* __restrict__ w21, const float* __restrict__ w22,
    const float* __restrict__ w31, const float* __restrict__ w32,
    const float* __restrict__ b11, const float* __restrict__ g1, const float* __restrict__ be1, const float* __restrict__ b12,
    const float* __restrict__ b21, const float* __restrict__ g2, const float* __restrict__ be2, const float* __restrict__ b22,
    const float* __restrict__ b31, const float* __restrict__ g3, const float* __restrict__ be3, const float* __restrict__ b32,
    ushortT* __restrict__ Wt, float* __restrict__ addv)
{
    int bid = blockIdx.x, t = threadIdx.x;
    const float rs = rsqrtf(1.0f + 1e-5f);
    if (bid < 384) {
        int idx = bid * 256 + t;             // 0..98303
        int m = idx >> 14;                   // matrix 0..5
        int r = idx & 16383;
        int k = r & 127;
        int n = r >> 7;
        const float* W = (m == 0) ? w11 : (m == 1) ? w12 : (m == 2) ? w21
                       : (m == 3) ? w22 : (m == 4) ? w31 : w32;
        float v = W[k * 128 + n];
        if ((m & 1) == 0) {                  // a "w1": fold BN scale per out-col n
            const float* gm = (m == 0) ? g1 : (m == 2) ? g2 : g3;
            v *= gm[n] * rs;
        }
        Wt[m * 16384 + n * 128 + k] = f2bf(v);
    } else if (bid == 384) {                 // gemm1 adds: b1*s + beta
        if (t < 384) {
            int L = t >> 7, n = t & 127;
            const float* bb = (L == 0) ? b11 : (L == 1) ? b21 : b31;
            const float* gm = (L == 0) ? g1 : (L == 1) ? g2 : g3;
            const float* be = (L == 0) ? be1 : (L == 1) ? be2 : be3;
            float s = gm[n] * rs;
            addv[(2 * L) * 128 + n] = bb[n] * s + be[n];
        }
    } else {                                 // gemm2 adds: b2
        if (t < 384) {
            int L = t >> 7, n = t & 127;
            const float* bb = (L == 0) ? b12 : (L == 1) ? b22 : b32;
            addv[(2 * L + 1) * 128 + n] = bb[n];
        }
    }
}

// ---------------- x (fp32) -> bf16, plus zeroed padding rows ----------------
__global__ __launch_bounds__(256) void k_cvt(const float* __restrict__ X, ushortT* __restrict__ Y) {
    size_t i = ((size_t)blockIdx.x * 256 + threadIdx.x) * 4;
    if (i >= (size_t)MPAD * 128) return;
    unsigned long long o = 0ull;
    if (i < (size_t)N_NODES * 128) {
        float4 v = *(const float4*)&X[i];
        o = (unsigned long long)f2bf(v.x)
          | ((unsigned long long)f2bf(v.y) << 16)
          | ((unsigned long long)f2bf(v.z) << 32)
          | ((unsigned long long)f2bf(v.w) << 48);
    }
    *(unsigned long long*)&Y[i] = o;
}

// ------- bucket binning: scatter (src,dst) into dst-range buckets, L2-local writes -------
__global__ __launch_bounds__(256) void kb_scatter(const int* __restrict__ src, const int* __restrict__ dst,
                                                  int* __restrict__ gcur, int2* __restrict__ ebin) {
    __shared__ int lcnt[NBUCK];
    __shared__ int lbase[NBUCK];
    int t = threadIdx.x;
    int e0 = blockIdx.x * (N_EDGES / 256);
    int e1 = e0 + (N_EDGES / 256);
    for (int i = t; i < NBUCK; i += 256) lcnt[i] = 0;
    __syncthreads();
    for (int e = e0 + t; e < e1; e += 256) atomicAdd(&lcnt[dst[e] >> 7], 1);
    __syncthreads();
    for (int i = t; i < NBUCK; i += 256) {
        int c = lcnt[i];
        lbase[i] = c ? atomicAdd(&gcur[i], c) : 0;
    }
    __syncthreads();
    for (int i = t; i < NBUCK; i += 256) lcnt[i] = 0;
    __syncthreads();
    for (int e = e0 + t; e < e1; e += 256) {
        int d = dst[e];
        int b = d >> 7;
        int off = atomicAdd(&lcnt[b], 1);
        ebin[(size_t)b * BCAP + lbase[b] + off] = make_int2(src[e], d);
    }
}

// ------- per-bucket degree count: LDS histogram, no global atomics -------
__global__ __launch_bounds__(256) void kb_count(const int2* __restrict__ ebin, const int* __restrict__ gcur,
                                                int* __restrict__ deg) {
    __shared__ int cnt[128];
    int b = blockIdx.x, t = threadIdx.x;
    if (t < 128) cnt[t] = 0;
    __syncthreads();
    int m = gcur[b];
    const int2* eb = ebin + (size_t)b * BCAP;
    for (int e = t; e < m; e += 256) atomicAdd(&cnt[eb[e].y & 127], 1);
    __syncthreads();
    if (t < 128) {
        int node = b * 128 + t;
        if (node < N_NODES) deg[node] = cnt[t];
    }
}

__global__ __launch_bounds__(1024) void k_scan1(const int* __restrict__ deg, int* __restrict__ tscan,
                                                int* __restrict__ bsum) {
    __shared__ int s[1024];
    int t = threadIdx.x;
    int i = blockIdx.x * 1024 + t;
    int v = (i < N_NODES) ? ((deg[i] + 7) & ~7) : 0;   // padded degree
    s[t] = v;
    __syncthreads();
    for (int off = 1; off < 1024; off <<= 1) {
        int tmp = (t >= off) ? s[t - off] : 0;
        __syncthreads();
        s[t] += tmp;
        __syncthreads();
    }
    tscan[i] = s[t];
    if (t == 1023) bsum[blockIdx.x] = s[1023];
}

__global__ void k_scan2(const int* __restrict__ bsum, int* __restrict__ boff) {
    if (threadIdx.x == 0 && blockIdx.x == 0) {
        int run = 0;
        for (int b = 0; b < 98; ++b) { boff[b] = run; run += bsum[b]; }
    }
}

__global__ __launch_bounds__(256) void k_scan3(const int* __restrict__ tscan, const int* __restrict__ boff,
                                               int* __restrict__ pstart) {
    int i = blockIdx.x * 256 + threadIdx.x;
    if (i > N_NODES) return;
    pstart[i] = (i == 0) ? 0 : tscan[i - 1] + boff[(i - 1) >> 10];
}

// ------- per-bucket CSR fill + inline padding to x8 with node N_NODES (zero row) -------
__global__ __launch_bounds__(256) void kb_fill(const int2* __restrict__ ebin, const int* __restrict__ gcur,
                                               const int* __restrict__ pstart, int* __restrict__ col) {
    __shared__ int ps[128];
    __shared__ int cur[128];
    int b = blockIdx.x, t = threadIdx.x;
    if (t < 128) {
        int node = b * 128 + t;
        ps[t] = (node < N_NODES) ? pstart[node] : 0;
        cur[t] = 0;
    }
    __syncthreads();
    int m = gcur[b];
    const int2* eb = ebin + (size_t)b * BCAP;
    for (int e = t; e < m; e += 256) {
        int2 sd = eb[e];
        int idx = sd.y & 127;
        int pos = ps[idx] + atomicAdd(&cur[idx], 1);
        col[pos] = sd.x;
    }
    __syncthreads();
    if (t < 128) {
        int node = b * 128 + t;
        if (node < N_NODES) {
            int s = ps[t] + cur[t];          // cur == degree after fill
            int e = pstart[node + 1];
            for (int j = s; j < e; ++j) col[j] = N_NODES;
        }
    }
}

// ------- aggregation (bf16): T[i] = bf16(X[i] + sum_j X[col[j]]), unroll-8 branch-free -------
__global__ __launch_bounds__(256) void k_agg(const ushortT* __restrict__ X, const int* __restrict__ pstart,
                                             const int* __restrict__ col, ushortT* __restrict__ T) {
    int gid = blockIdx.x * 4 + (threadIdx.x >> 6);
    int lane = threadIdx.x & 63;
    if (gid >= MPAD) return;
    if (gid >= N_NODES) {                    // zero padding rows (MFMA A-operand hygiene)
        *(unsigned int*)&T[(size_t)gid * 128 + lane * 2] = 0u;
        return;
    }
    int lo = pstart[gid], hi = pstart[gid + 1];
    unsigned int v = *(const unsigned int*)&X[(size_t)gid * 128 + lane * 2];
    float ax = bf2f((ushortT)(v & 0xffff));
    float ay = bf2f((ushortT)(v >> 16));
    for (int j = lo; j < hi; j += 8) {       // (hi-lo) % 8 == 0 by construction
        int4 c0 = *(const int4*)&col[j];
        int4 c1 = *(const int4*)&col[j + 4];
        unsigned int u0 = *(const unsigned int*)&X[(size_t)c0.x * 128 + lane * 2];
        unsigned int u1 = *(const unsigned int*)&X[(size_t)c0.y * 128 + lane * 2];
        unsigned int u2 = *(const unsigned int*)&X[(size_t)c0.z * 128 + lane * 2];
        unsigned int u3 = *(const unsigned int*)&X[(size_t)c0.w * 128 + lane * 2];
        unsigned int u4 = *(const unsigned int*)&X[(size_t)c1.x * 128 + lane * 2];
        unsigned int u5 = *(const unsigned int*)&X[(size_t)c1.y * 128 + lane * 2];
        unsigned int u6 = *(const unsigned int*)&X[(size_t)c1.z * 128 + lane * 2];
        unsigned int u7 = *(const unsigned int*)&X[(size_t)c1.w * 128 + lane * 2];
        ax += bf2f((ushortT)(u0 & 0xffff)) + bf2f((ushortT)(u1 & 0xffff))
            + bf2f((ushortT)(u2 & 0xffff)) + bf2f((ushortT)(u3 & 0xffff))
            + bf2f((ushortT)(u4 & 0xffff)) + bf2f((ushortT)(u5 & 0xffff))
            + bf2f((ushortT)(u6 & 0xffff)) + bf2f((ushortT)(u7 & 0xffff));
        ay += bf2f((ushortT)(u0 >> 16)) + bf2f((ushortT)(u1 >> 16))
            + bf2f((ushortT)(u2 >> 16)) + bf2f((ushortT)(u3 >> 16))
            + bf2f((ushortT)(u4 >> 16)) + bf2f((ushortT)(u5 >> 16))
            + bf2f((ushortT)(u6 >> 16)) + bf2f((ushortT)(u7 >> 16));
    }
    unsigned int o = ((unsigned int)f2bf(ay) << 16) | (unsigned int)f2bf(ax);
    *(unsigned int*)&T[(size_t)gid * 128 + lane * 2] = o;
}

// ======== FUSED DOUBLE-GEMM + POOL: C = relu(relu(A@W1+add1)@W2+add2); pool C by graph.
// 64 rows/block, 4 waves x 16 rows. LDS: W (34.8KB, W1->W2) + H tile (17.4KB, reused as pool buf).
__global__ __launch_bounds__(256) void k_gemm_f(const ushortT* __restrict__ A,
                                                const ushortT* __restrict__ W1, const float* __restrict__ add1,
                                                const ushortT* __restrict__ W2, const float* __restrict__ add2,
                                                ushortT* __restrict__ C, const int* __restrict__ batch,
                                                float* __restrict__ P, int off) {
    __shared__ ushortT wlds[128 * 136];      // staged weights (reused: W1 -> W2)
    __shared__ ushortT hlds[64 * 136];       // H tile; first 3KB reused as pool buffer
    float* pws = (float*)hlds;               // 6 slots x 128 fp32
    int tid = threadIdx.x;
    int wave = tid >> 6, lane = tid & 63;
    int quad = lane >> 4, l16 = lane & 15;
    int blk0 = blockIdx.x * 64;
    int base = blk0 + wave * 16;

    // A-fragments from global first (overlaps W1 staging)
    bf16x8 af[4];
#pragma unroll
    for (int kc = 0; kc < 4; ++kc)
        af[kc] = *(const bf16x8*)&A[(size_t)(base + l16) * 128 + kc * 32 + quad * 8];

    // stage W1
#pragma unroll
    for (int it = 0; it < 8; ++it) {
        int idx = (it * 256 + tid) * 8;
        int n = idx >> 7, k = idx & 127;
        *(uint4v*)&wlds[n * 136 + k] = *(const uint4v*)&W1[idx];
    }
    __syncthreads();

    // gemm1
    f32x4 acc[8];
#pragma unroll
    for (int c = 0; c < 8; ++c) acc[c] = (f32x4){0.f, 0.f, 0.f, 0.f};
#pragma unroll
    for (int kc = 0; kc < 4; ++kc) {
#pragma unroll
        for (int c = 0; c < 8; ++c) {
            bf16x8 b1 = *(const bf16x8*)&wlds[(c * 16 + l16) * 136 + kc * 32 + quad * 8];
            acc[c] = __builtin_amdgcn_mfma_f32_16x16x32_bf16(af[kc], b1, acc[c], 0, 0, 0);
        }
    }
    __syncthreads();                         // all waves done reading W1

    // stage W2 over W1's region, and write H into wave-private tile
#pragma unroll
    for (int it = 0; it < 8; ++it) {
        int idx = (it * 256 + tid) * 8;
        int n = idx >> 7, k = idx & 127;
        *(uint4v*)&wlds[n * 136 + k] = *(const uint4v*)&W2[idx];
    }
    ushortT* hw = hlds + (wave * 16) * 136;
#pragma unroll
    for (int c = 0; c < 8; ++c) {
        int n = c * 16 + l16;
        float ad = add1[n];
#pragma unroll
        for (int r = 0; r < 4; ++r) {
            float y = acc[c][r] + ad;
            y = y > 0.f ? y : 0.f;
            hw[(quad * 4 + r) * 136 + n] = f2bf(y);
        }
    }
    __syncthreads();                         // W2 staged, H tiles written

    // load H fragments for gemm2 (from own wave's window)
#pragma unroll
    for (int kc = 0; kc < 4; ++kc)
        af[kc] = *(const bf16x8*)&hw[l16 * 136 + kc * 32 + quad * 8];
    __syncthreads();                         // all waves' H frags in regs -> hlds reusable

    // zero pool buffer (aliases hlds)
    for (int i = tid; i < 6 * 128; i += 256) pws[i] = 0.f;
    __syncthreads();

    // gemm2
#pragma unroll
    for (int c = 0; c < 8; ++c) acc[c] = (f32x4){0.f, 0.f, 0.f, 0.f};
#pragma unroll
    for (int kc = 0; kc < 4; ++kc) {
#pragma unroll
        for (int c = 0; c < 8; ++c) {
            bf16x8 b2 = *(const bf16x8*)&wlds[(c * 16 + l16) * 136 + kc * 32 + quad * 8];
            acc[c] = __builtin_amdgcn_mfma_f32_16x16x32_bf16(af[kc], b2, acc[c], 0, 0, 0);
        }
    }

    // epilogue: store C = relu(acc + add2) and accumulate pool partials
    int g0blk = batch[blk0 < N_NODES ? blk0 : (N_NODES - 1)];
    bool anyrow = (base < N_NODES);
    int gr[4] = {-1, -1, -1, -1};
    if (anyrow) {
#pragma unroll
        for (int r = 0; r < 4; ++r) {
            int row = base + quad * 4 + r;
            gr[r] = (row < N_NODES) ? batch[row] : -1;
        }
    }
    bool fast = (base + 15 < N_NODES) && (batch[base] == batch[base + 15]);

#pragma unroll
    for (int c = 0; c < 8; ++c) {
        int n = c * 16 + l16;
        float ad = add2[n];
        float ys[4];
        float s = 0.f;
#pragma unroll
        for (int r = 0; r < 4; ++r) {
            int row = base + quad * 4 + r;
            float y = 0.f;
            if (row < N_NODES) {
                y = acc[c][r] + ad;
                y = y > 0.f ? y : 0.f;
                C[(size_t)row * 128 + n] = f2bf(y);
            }
            ys[r] = y;
            s += y;
        }
        if (fast) {
            s += __shfl_xor(s, 16);
            s += __shfl_xor(s, 32);
            if (quad == 0) {
                int slot = gr[0] - g0blk;
                if (slot < 6) atomicAdd(&pws[slot * 128 + n], s);
                else atomicAdd(&P[gr[0] * 384 + off + n], s);
            }
        } else if (anyrow) {
#pragma unroll
            for (int r = 0; r < 4; ++r) {
                if (gr[r] >= 0) {
                    int slot = gr[r] - g0blk;
                    if (slot < 6) atomicAdd(&pws[slot * 128 + n], ys[r]);
                    else atomicAdd(&P[gr[r] * 384 + off + n], ys[r]);
                }
            }
        }
    }
    __syncthreads();

    // flush pool partials (one global atomic per nonzero (slot, dim))
    for (int i = tid; i < 6 * 128; i += 256) {
        float v = pws[i];
        if (v != 0.f) {
            int g = g0blk + (i >> 7);
            atomicAdd(&P[g * 384 + off + (i & 127)], v);
        }
    }
}

// ---------------- head: out = relu(P @ W1 + b1) @ W2 + b2  (all fp32) ------------
__global__ __launch_bounds__(384) void k_head(const float* __restrict__ P, const float* __restrict__ W1,
                                              const float* __restrict__ B1, const float* __restrict__ W2,
                                              const float* __restrict__ B2, float* __restrict__ out) {
    __shared__ float pr[384];
    __shared__ float qr[384];
    int g = blockIdx.x, t = threadIdx.x;
    pr[t] = P[g * 384 + t];
    __syncthreads();
    float a = 0.f;
    for (int k = 0; k < 384; ++k) a += pr[k] * W1[k * 384 + t];
    a += B1[t];
    qr[t] = a > 0.f ? a : 0.f;
    __syncthreads();
    if (t < 10) {
        float o = 0.f;
        for (int k = 0; k < 384; ++k) o += qr[k] * W2[k * 10 + t];
        o += B2[t];
        out[g * 10 + t] = o;
    }
}

extern "C" void kernel_launch(void* const* d_in, const int* in_sizes, int n_in,
                              void* d_out, int out_size, void* d_ws, size_t ws_size,
                              hipStream_t stream) {
    const float* x     = (const float*)d_in[0];
    const int*   ei    = (const int*)d_in[1];
    const int*   srcA  = ei;
    const int*   dstA  = ei + N_EDGES;
    const int*   batch = (const int*)d_in[2];
    const float* c1_w1 = (const float*)d_in[3];
    const float* c1_b1 = (const float*)d_in[4];
    const float* c1_g  = (const float*)d_in[5];
    const float* c1_be = (const float*)d_in[6];
    const float* c1_w2 = (const float*)d_in[7];
    const float* c1_b2 = (const float*)d_in[8];
    const float* c2_w1 = (const float*)d_in[9];
    const float* c2_b1 = (const float*)d_in[10];
    const float* c2_g  = (const float*)d_in[11];
    const float* c2_be = (const float*)d_in[12];
    const float* c2_w2 = (const float*)d_in[13];
    const float* c2_b2 = (const float*)d_in[14];
    const float* c3_w1 = (const float*)d_in[15];
    const float* c3_b1 = (const float*)d_in[16];
    const float* c3_g  = (const float*)d_in[17];
    const float* c3_be = (const float*)d_in[18];
    const float* c3_w2 = (const float*)d_in[19];
    const float* c3_b2 = (const float*)d_in[20];
    const float* l1w   = (const float*)d_in[21];
    const float* l1b   = (const float*)d_in[22];
    const float* l2w   = (const float*)d_in[23];
    const float* l2b   = (const float*)d_in[24];
    float* out = (float*)d_out;

    size_t o = 0;
    char* base = (char*)d_ws;
    auto alloc = [&](size_t n) -> char* {
        char* p = base + o;
        o += (n + 255) & ~(size_t)255;
        return p;
    };
    ushortT* Wt    = (ushortT*)alloc(6 * 16384 * 2);
    float*   addv  = (float*)alloc(6 * 128 * 4);
    int*     deg   = (int*)alloc((size_t)N_NODES * 4);
    int*     gcur  = (int*)alloc((size_t)NBUCK * 4);
    int*     tscan = (int*)alloc((size_t)100352 * 4);
    int*     bsum  = (int*)alloc(98 * 4);
    int*     boff  = (int*)alloc(98 * 4);
    int*     pst   = (int*)alloc((size_t)(N_NODES + 1) * 4);
    int*     colA  = (int*)alloc((size_t)COL_CAP * 4);
    ushortT* bufA  = (ushortT*)alloc((size_t)MPAD * 128 * 2);   // agg out; ebin aliases this
    ushortT* bufB  = (ushortT*)alloc((size_t)MPAD * 128 * 2);   // L0/L2 out
    ushortT* bufC  = (ushortT*)alloc((size_t)MPAD * 128 * 2);   // x(bf16) / L1 out
    float*   pbuf  = (float*)alloc((size_t)N_GRAPHS * 384 * 4);
    int2*    ebin  = (int2*)bufA;   // 782*3072*8 = 19.2 MB <= 25.6 MB; dead before first k_agg

    hipMemsetAsync(gcur, 0, (size_t)NBUCK * 4, stream);
    hipMemsetAsync(pbuf, 0, (size_t)N_GRAPHS * 384 * 4, stream);
    // gather pad row (index N_NODES) must be zero in bufB (used as gather input in L1)
    hipMemsetAsync(bufB + (size_t)N_NODES * 128, 0, 256, stream);

    k_prep<<<386, 256, 0, stream>>>(c1_w1, c1_w2, c2_w1, c2_w2, c3_w1, c3_w2,
                                    c1_b1, c1_g, c1_be, c1_b2,
                                    c2_b1, c2_g, c2_be, c2_b2,
                                    c3_b1, c3_g, c3_be, c3_b2,
                                    Wt, addv);
    k_cvt<<<(MPAD * 128 / 4 + 255) / 256, 256, 0, stream>>>(x, bufC);
    kb_scatter<<<256, 256, 0, stream>>>(srcA, dstA, gcur, ebin);
    kb_count<<<NBUCK, 256, 0, stream>>>(ebin, gcur, deg);
    k_scan1<<<98, 1024, 0, stream>>>(deg, tscan, bsum);
    k_scan2<<<1, 64, 0, stream>>>(bsum, boff);
    k_scan3<<<391, 256, 0, stream>>>(tscan, boff, pst);
    kb_fill<<<NBUCK, 256, 0, stream>>>(ebin, gcur, pst, colA);

    // L0: bufC -> (agg) bufA -> (fused gemm+pool) bufB ; L1: bufB -> bufA -> bufC ; L2: bufC -> bufA -> bufB
    k_agg<<<MPAD / 4, 256, 0, stream>>>(bufC, pst, colA, bufA);
    k_gemm_f<<<MPAD / 64, 256, 0, stream>>>(bufA, Wt + 0 * 16384, addv + 0 * 128,
                                            Wt + 1 * 16384, addv + 1 * 128, bufB, batch, pbuf, 0);
    k_agg<<<MPAD / 4, 256, 0, stream>>>(bufB, pst, colA, bufA);
    k_gemm_f<<<MPAD / 64, 256, 0, stream>>>(bufA, Wt + 2 * 16384, addv + 2 * 128,
                                            Wt + 3 * 16384, addv + 3 * 128, bufC, batch, pbuf, 128);
    k_agg<<<MPAD / 4, 256, 0, stream>>>(bufC, pst, colA, bufA);
    k_gemm_f<<<MPAD / 64, 256, 0, stream>>>(bufA, Wt + 4 * 16384, addv + 4 * 128,
                                            Wt + 5 * 16384, addv + 5 * 128, bufB, batch, pbuf, 256);

    k_head<<<N_GRAPHS, 384, 0, stream>>>(pbuf, l1w, l1b, l2w, l2b, out);
}

// Round 10
// 516.201 us; speedup vs baseline: 1.6067x; 1.0481x over previous
//
#include <hip/hip_runtime.h>

#define N_NODES 100000
#define N_EDGES 1600000
#define N_GRAPHS 512
#define MPAD 100096      // 782 * 128 (also 1564 * 64)
#define NBUCK 782        // buckets of 128 nodes (dst >> 7)
#define BCAP 3072        // per-bucket ebin capacity; mean 2046, sigma ~45 -> 22 sigma margin
#define BCOL 3968        // per-bucket col window: BCAP + 7*128 pad worst case

typedef unsigned short ushortT;
typedef __attribute__((ext_vector_type(8))) short bf16x8;
typedef __attribute__((ext_vector_type(4))) float f32x4;
typedef __attribute__((ext_vector_type(4))) unsigned int uint4v;

__device__ inline float bf2f(ushortT u) {
    unsigned int x = ((unsigned int)u) << 16;
    return __builtin_bit_cast(float, x);
}
__device__ inline ushortT f2bf(float f) {
    unsigned int x = __builtin_bit_cast(unsigned int, f);
    unsigned int r = (x + 0x7fffu + ((x >> 16) & 1u)) >> 16;
    return (ushortT)r;
}

// ======== MEGA-PROLOGUE: scatter | weight-prep | pbuf zero | bufB pad zero | x->bf16 cvt
// All roles independent; one launch replaces 5 (launch gap ~5us each).
__global__ __launch_bounds__(256) void k_pre(
    const float* __restrict__ x, const int* __restrict__ src, const int* __restrict__ dst,
    const float* __restrict__ w11, const float* __restrict__ w12,
    const float* __restrict__ w21, const float* __restrict__ w22,
    const float* __restrict__ w31, const float* __restrict__ w32,
    const float* __restrict__ b11, const float* __restrict__ g1, const float* __restrict__ be1, const float* __restrict__ b12,
    const float* __restrict__ b21, const float* __restrict__ g2, const float* __restrict__ be2, const float* __restrict__ b22,
    const float* __restrict__ b31, const float* __restrict__ g3, const float* __restrict__ be3, const float* __restrict__ b32,
    int* __restrict__ gcur, int2* __restrict__ ebin,
    ushortT* __restrict__ Wt, float* __restrict__ addv,
    ushortT* __restrict__ Ybf, ushortT* __restrict__ bufB, float* __restrict__ pbuf)
{
    __shared__ int lcnt[NBUCK];
    __shared__ int lbase[NBUCK];
    int bid = blockIdx.x, t = threadIdx.x;

    if (bid < 256) {
        // -------- edge scatter into dst-range buckets (L2-local append streams) --------
        int e0 = bid * (N_EDGES / 256);
        int e1 = e0 + (N_EDGES / 256);
        for (int i = t; i < NBUCK; i += 256) lcnt[i] = 0;
        __syncthreads();
        for (int e = e0 + t; e < e1; e += 256) atomicAdd(&lcnt[dst[e] >> 7], 1);
        __syncthreads();
        for (int i = t; i < NBUCK; i += 256) {
            int c = lcnt[i];
            lbase[i] = c ? atomicAdd(&gcur[i], c) : 0;
        }
        __syncthreads();
        for (int i = t; i < NBUCK; i += 256) lcnt[i] = 0;
        __syncthreads();
        for (int e = e0 + t; e < e1; e += 256) {
            int d = dst[e];
            int b = d >> 7;
            int off = atomicAdd(&lcnt[b], 1);
            ebin[(size_t)b * BCAP + lbase[b] + off] = make_int2(src[e], d);
        }
    } else if (bid < 642) {
        // -------- weight transpose (fold BN scale) + add vectors --------
        int pb = bid - 256;
        const float rs = rsqrtf(1.0f + 1e-5f);
        if (pb < 384) {
            int idx = pb * 256 + t;
            int m = idx >> 14;
            int r = idx & 16383;
            int k = r & 127;
            int n = r >> 7;
            const float* W = (m == 0) ? w11 : (m == 1) ? w12 : (m == 2) ? w21
                           : (m == 3) ? w22 : (m == 4) ? w31 : w32;
            float v = W[k * 128 + n];
            if ((m & 1) == 0) {
                const float* gm = (m == 0) ? g1 : (m == 2) ? g2 : g3;
                v *= gm[n] * rs;
            }
            Wt[m * 16384 + n * 128 + k] = f2bf(v);
        } else if (pb == 384) {
            if (t < 384) {
                int L = t >> 7, n = t & 127;
                const float* bb = (L == 0) ? b11 : (L == 1) ? b21 : b31;
                const float* gm = (L == 0) ? g1 : (L == 1) ? g2 : g3;
                const float* be = (L == 0) ? be1 : (L == 1) ? be2 : be3;
                float s = gm[n] * rs;
                addv[(2 * L) * 128 + n] = bb[n] * s + be[n];
            }
        } else {
            if (t < 384) {
                int L = t >> 7, n = t & 127;
                const float* bb = (L == 0) ? b12 : (L == 1) ? b22 : b32;
                addv[(2 * L + 1) * 128 + n] = bb[n];
            }
        }
    } else if (bid < 690) {
        // -------- zero pbuf (512*384 fp32, exact: 48 blocks x 256 x float4) --------
        int i4 = (bid - 642) * 256 + t;
        *(float4*)&pbuf[i4 * 4] = make_float4(0.f, 0.f, 0.f, 0.f);
    } else if (bid == 690) {
        // -------- zero bufB pad rows [N_NODES, MPAD): 96 rows = 1536 u64 --------
        unsigned long long* p = (unsigned long long*)(bufB + (size_t)N_NODES * 128);
#pragma unroll
        for (int i = 0; i < 6; ++i) p[t + i * 256] = 0ull;
    } else {
        // -------- x (fp32) -> bf16 + zero pad rows --------
        size_t i = ((size_t)(bid - 691) * 256 + t) * 4;
        unsigned long long o = 0ull;
        if (i < (size_t)N_NODES * 128) {
            float4 v = *(const float4*)&x[i];
            o = (unsigned long long)f2bf(v.x)
              | ((unsigned long long)f2bf(v.y) << 16)
              | ((unsigned long long)f2bf(v.z) << 32)
              | ((unsigned long long)f2bf(v.w) << 48);
        }
        *(unsigned long long*)&Ybf[i] = o;
    }
}

// ======== per-bucket CSR build: histogram + LDS scan + place + pad (replaces count+scan1/2/3+fill)
__global__ __launch_bounds__(256) void kb_build(const int2* __restrict__ ebin, const int* __restrict__ gcur,
                                                int* __restrict__ col, int* __restrict__ pstart,
                                                int* __restrict__ pend) {
    __shared__ int cnt[128];
    __shared__ int pc[128];
    __shared__ int ps[128];
    __shared__ int cur[128];
    int b = blockIdx.x, t = threadIdx.x;
    if (t < 128) cnt[t] = 0;
    __syncthreads();
    int m = gcur[b];
    const int2* eb = ebin + (size_t)b * BCAP;
    for (int e = t; e < m; e += 256) atomicAdd(&cnt[eb[e].y & 127], 1);
    __syncthreads();
    if (t < 128) pc[t] = (cnt[t] + 7) & ~7;      // padded degree
    __syncthreads();
    // inclusive scan over pc[0..127]
    for (int off = 1; off < 128; off <<= 1) {
        int v = (t < 128 && t >= off) ? pc[t - off] : 0;
        __syncthreads();
        if (t < 128) pc[t] += v;
        __syncthreads();
    }
    if (t < 128) {
        int padded = (cnt[t] + 7) & ~7;
        int start = b * BCOL + pc[t] - padded;   // exclusive prefix
        ps[t] = start;
        cur[t] = 0;
        int node = b * 128 + t;
        if (node < N_NODES) {
            pstart[node] = start;
            pend[node] = start + padded;
        }
    }
    __syncthreads();
    for (int e = t; e < m; e += 256) {
        int2 sd = eb[e];
        int idx = sd.y & 127;
        int pos = ps[idx] + atomicAdd(&cur[idx], 1);
        col[pos] = sd.x;
    }
    __syncthreads();
    if (t < 128) {
        int s = ps[t] + cnt[t];
        int e = ps[t] + ((cnt[t] + 7) & ~7);
        for (int j = s; j < e; ++j) col[j] = N_NODES;   // pad with guaranteed-zero row
    }
}

// ------- aggregation (bf16): T[i] = bf16(X[i] + sum_j X[col[j]]), unroll-8 branch-free -------
__global__ __launch_bounds__(256) void k_agg(const ushortT* __restrict__ X, const int* __restrict__ pstart,
                                             const int* __restrict__ pend, const int* __restrict__ col,
                                             ushortT* __restrict__ T) {
    int gid = blockIdx.x * 4 + (threadIdx.x >> 6);
    int lane = threadIdx.x & 63;
    if (gid >= MPAD) return;
    if (gid >= N_NODES) {                    // zero padding rows (MFMA A-operand hygiene)
        *(unsigned int*)&T[(size_t)gid * 128 + lane * 2] = 0u;
        return;
    }
    int lo = pstart[gid], hi = pend[gid];
    unsigned int v = *(const unsigned int*)&X[(size_t)gid * 128 + lane * 2];
    float ax = bf2f((ushortT)(v & 0xffff));
    float ay = bf2f((ushortT)(v >> 16));
    for (int j = lo; j < hi; j += 8) {       // (hi-lo) % 8 == 0 by construction
        int4 c0 = *(const int4*)&col[j];
        int4 c1 = *(const int4*)&col[j + 4];
        unsigned int u0 = *(const unsigned int*)&X[(size_t)c0.x * 128 + lane * 2];
        unsigned int u1 = *(const unsigned int*)&X[(size_t)c0.y * 128 + lane * 2];
        unsigned int u2 = *(const unsigned int*)&X[(size_t)c0.z * 128 + lane * 2];
        unsigned int u3 = *(const unsigned int*)&X[(size_t)c0.w * 128 + lane * 2];
        unsigned int u4 = *(const unsigned int*)&X[(size_t)c1.x * 128 + lane * 2];
        unsigned int u5 = *(const unsigned int*)&X[(size_t)c1.y * 128 + lane * 2];
        unsigned int u6 = *(const unsigned int*)&X[(size_t)c1.z * 128 + lane * 2];
        unsigned int u7 = *(const unsigned int*)&X[(size_t)c1.w * 128 + lane * 2];
        ax += bf2f((ushortT)(u0 & 0xffff)) + bf2f((ushortT)(u1 & 0xffff))
            + bf2f((ushortT)(u2 & 0xffff)) + bf2f((ushortT)(u3 & 0xffff))
            + bf2f((ushortT)(u4 & 0xffff)) + bf2f((ushortT)(u5 & 0xffff))
            + bf2f((ushortT)(u6 & 0xffff)) + bf2f((ushortT)(u7 & 0xffff));
        ay += bf2f((ushortT)(u0 >> 16)) + bf2f((ushortT)(u1 >> 16))
            + bf2f((ushortT)(u2 >> 16)) + bf2f((ushortT)(u3 >> 16))
            + bf2f((ushortT)(u4 >> 16)) + bf2f((ushortT)(u5 >> 16))
            + bf2f((ushortT)(u6 >> 16)) + bf2f((ushortT)(u7 >> 16));
    }
    unsigned int o = ((unsigned int)f2bf(ay) << 16) | (unsigned int)f2bf(ax);
    *(unsigned int*)&T[(size_t)gid * 128 + lane * 2] = o;
}

// ======== FUSED DOUBLE-GEMM + POOL: C = relu(relu(A@W1+add1)@W2+add2); pool into P.
// 64 rows/block, 4 waves x 16 rows. LDS: W (34.8KB, W1->W2) + H/A tile (17.4KB, also pool buf).
// A staged through LDS with coalesced 1KB loads (vs 16-line scattered frag loads).
__global__ __launch_bounds__(256) void k_gemm_f(const ushortT* __restrict__ A,
                                                const ushortT* __restrict__ W1, const float* __restrict__ add1,
                                                const ushortT* __restrict__ W2, const float* __restrict__ add2,
                                                ushortT* __restrict__ C, const int* __restrict__ batch,
                                                float* __restrict__ P, int off) {
    __shared__ ushortT wlds[128 * 136];      // staged weights (reused: W1 -> W2)
    __shared__ ushortT hlds[64 * 136];       // A then H tile; first 3KB reused as pool buffer
    float* pws = (float*)hlds;               // 6 slots x 128 fp32
    int tid = threadIdx.x;
    int wave = tid >> 6, lane = tid & 63;
    int quad = lane >> 4, l16 = lane & 15;
    int blk0 = blockIdx.x * 64;
    int base = blk0 + wave * 16;
    ushortT* hw = hlds + (wave * 16) * 136;

    // stage A into wave-private LDS window: each instruction reads 4 consecutive rows = 1KB coalesced
    {
        int r = lane >> 4;
        int ck = (lane & 15) * 8;
#pragma unroll
        for (int i = 0; i < 4; ++i) {
            int row = i * 4 + r;
            uint4v v = *(const uint4v*)&A[(size_t)(base + row) * 128 + ck];
            *(uint4v*)&hw[row * 136 + ck] = v;
        }
    }
    // stage W1 (cooperative)
#pragma unroll
    for (int it = 0; it < 8; ++it) {
        int idx = (it * 256 + tid) * 8;
        int n = idx >> 7, k = idx & 127;
        *(uint4v*)&wlds[n * 136 + k] = *(const uint4v*)&W1[idx];
    }
    __syncthreads();

    // A-frags from LDS
    bf16x8 af[4];
#pragma unroll
    for (int kc = 0; kc < 4; ++kc)
        af[kc] = *(const bf16x8*)&hw[l16 * 136 + kc * 32 + quad * 8];

    // gemm1
    f32x4 acc[8];
#pragma unroll
    for (int c = 0; c < 8; ++c) acc[c] = (f32x4){0.f, 0.f, 0.f, 0.f};
#pragma unroll
    for (int kc = 0; kc < 4; ++kc) {
#pragma unroll
        for (int c = 0; c < 8; ++c) {
            bf16x8 b1 = *(const bf16x8*)&wlds[(c * 16 + l16) * 136 + kc * 32 + quad * 8];
            acc[c] = __builtin_amdgcn_mfma_f32_16x16x32_bf16(af[kc], b1, acc[c], 0, 0, 0);
        }
    }
    __syncthreads();                         // all waves done reading W1

    // stage W2 over W1's region; write H = relu(acc+add1) over own A window (A frags consumed)
#pragma unroll
    for (int it = 0; it < 8; ++it) {
        int idx = (it * 256 + tid) * 8;
        int n = idx >> 7, k = idx & 127;
        *(uint4v*)&wlds[n * 136 + k] = *(const uint4v*)&W2[idx];
    }
#pragma unroll
    for (int c = 0; c < 8; ++c) {
        int n = c * 16 + l16;
        float ad = add1[n];
#pragma unroll
        for (int r = 0; r < 4; ++r) {
            float y = acc[c][r] + ad;
            y = y > 0.f ? y : 0.f;
            hw[(quad * 4 + r) * 136 + n] = f2bf(y);
        }
    }
    __syncthreads();                         // W2 staged, H tiles written

    // H frags for gemm2
#pragma unroll
    for (int kc = 0; kc < 4; ++kc)
        af[kc] = *(const bf16x8*)&hw[l16 * 136 + kc * 32 + quad * 8];
    __syncthreads();                         // all H frags in regs -> hlds reusable as pool buf

    for (int i = tid; i < 6 * 128; i += 256) pws[i] = 0.f;
    __syncthreads();

    // gemm2
#pragma unroll
    for (int c = 0; c < 8; ++c) acc[c] = (f32x4){0.f, 0.f, 0.f, 0.f};
#pragma unroll
    for (int kc = 0; kc < 4; ++kc) {
#pragma unroll
        for (int c = 0; c < 8; ++c) {
            bf16x8 b2 = *(const bf16x8*)&wlds[(c * 16 + l16) * 136 + kc * 32 + quad * 8];
            acc[c] = __builtin_amdgcn_mfma_f32_16x16x32_bf16(af[kc], b2, acc[c], 0, 0, 0);
        }
    }

    // epilogue: optional store C = relu(acc + add2); accumulate pool partials
    int g0blk = batch[blk0 < N_NODES ? blk0 : (N_NODES - 1)];
    bool anyrow = (base < N_NODES);
    int gr[4] = {-1, -1, -1, -1};
    if (anyrow) {
#pragma unroll
        for (int r = 0; r < 4; ++r) {
            int row = base + quad * 4 + r;
            gr[r] = (row < N_NODES) ? batch[row] : -1;
        }
    }
    bool fast = (base + 15 < N_NODES) && (batch[base] == batch[base + 15]);

#pragma unroll
    for (int c = 0; c < 8; ++c) {
        int n = c * 16 + l16;
        float ad = add2[n];
        float ys[4];
        float s = 0.f;
#pragma unroll
        for (int r = 0; r < 4; ++r) {
            int row = base + quad * 4 + r;
            float y = 0.f;
            if (row < N_NODES) {
                y = acc[c][r] + ad;
                y = y > 0.f ? y : 0.f;
                if (C) C[(size_t)row * 128 + n] = f2bf(y);
            }
            ys[r] = y;
            s += y;
        }
        if (fast) {
            s += __shfl_xor(s, 16);
            s += __shfl_xor(s, 32);
            if (quad == 0) {
                int slot = gr[0] - g0blk;
                if (slot < 6) atomicAdd(&pws[slot * 128 + n], s);
                else atomicAdd(&P[gr[0] * 384 + off + n], s);
            }
        } else if (anyrow) {
#pragma unroll
            for (int r = 0; r < 4; ++r) {
                if (gr[r] >= 0) {
                    int slot = gr[r] - g0blk;
                    if (slot < 6) atomicAdd(&pws[slot * 128 + n], ys[r]);
                    else atomicAdd(&P[gr[r] * 384 + off + n], ys[r]);
                }
            }
        }
    }
    __syncthreads();

    // flush pool partials
    for (int i = tid; i < 6 * 128; i += 256) {
        float v = pws[i];
        if (v != 0.f) {
            int g = g0blk + (i >> 7);
            atomicAdd(&P[g * 384 + off + (i & 127)], v);
        }
    }
}

// ---------------- head: out = relu(P @ W1 + b1) @ W2 + b2  (all fp32) ------------
__global__ __launch_bounds__(384) void k_head(const float* __restrict__ P, const float* __restrict__ W1,
                                              const float* __restrict__ B1, const float* __restrict__ W2,
                                              const float* __restrict__ B2, float* __restrict__ out) {
    __shared__ float pr[384];
    __shared__ float qr[384];
    int g = blockIdx.x, t = threadIdx.x;
    pr[t] = P[g * 384 + t];
    __syncthreads();
    float a = 0.f;
    for (int k = 0; k < 384; ++k) a += pr[k] * W1[k * 384 + t];
    a += B1[t];
    qr[t] = a > 0.f ? a : 0.f;
    __syncthreads();
    if (t < 10) {
        float o = 0.f;
        for (int k = 0; k < 384; ++k) o += qr[k] * W2[k * 10 + t];
        o += B2[t];
        out[g * 10 + t] = o;
    }
}

extern "C" void kernel_launch(void* const* d_in, const int* in_sizes, int n_in,
                              void* d_out, int out_size, void* d_ws, size_t ws_size,
                              hipStream_t stream) {
    const float* x     = (const float*)d_in[0];
    const int*   ei    = (const int*)d_in[1];
    const int*   srcA  = ei;
    const int*   dstA  = ei + N_EDGES;
    const int*   batch = (const int*)d_in[2];
    const float* c1_w1 = (const float*)d_in[3];
    const float* c1_b1 = (const float*)d_in[4];
    const float* c1_g  = (const float*)d_in[5];
    const float* c1_be = (const float*)d_in[6];
    const float* c1_w2 = (const float*)d_in[7];
    const float* c1_b2 = (const float*)d_in[8];
    const float* c2_w1 = (const float*)d_in[9];
    const float* c2_b1 = (const float*)d_in[10];
    const float* c2_g  = (const float*)d_in[11];
    const float* c2_be = (const float*)d_in[12];
    const float* c2_w2 = (const float*)d_in[13];
    const float* c2_b2 = (const float*)d_in[14];
    const float* c3_w1 = (const float*)d_in[15];
    const float* c3_b1 = (const float*)d_in[16];
    const float* c3_g  = (const float*)d_in[17];
    const float* c3_be = (const float*)d_in[18];
    const float* c3_w2 = (const float*)d_in[19];
    const float* c3_b2 = (const float*)d_in[20];
    const float* l1w   = (const float*)d_in[21];
    const float* l1b   = (const float*)d_in[22];
    const float* l2w   = (const float*)d_in[23];
    const float* l2b   = (const float*)d_in[24];
    float* out = (float*)d_out;

    size_t o = 0;
    char* base = (char*)d_ws;
    auto alloc = [&](size_t n) -> char* {
        char* p = base + o;
        o += (n + 255) & ~(size_t)255;
        return p;
    };
    ushortT* Wt    = (ushortT*)alloc(6 * 16384 * 2);
    float*   addv  = (float*)alloc(6 * 128 * 4);
    int*     gcur  = (int*)alloc((size_t)NBUCK * 4);
    int*     pst   = (int*)alloc((size_t)N_NODES * 4);
    int*     pen   = (int*)alloc((size_t)N_NODES * 4);
    int*     colA  = (int*)alloc((size_t)NBUCK * BCOL * 4);
    ushortT* bufA  = (ushortT*)alloc((size_t)MPAD * 128 * 2);   // agg out; ebin aliases this
    ushortT* bufB  = (ushortT*)alloc((size_t)MPAD * 128 * 2);   // L0 out
    ushortT* bufC  = (ushortT*)alloc((size_t)MPAD * 128 * 2);   // x(bf16) / L1 out
    float*   pbuf  = (float*)alloc((size_t)N_GRAPHS * 384 * 4);
    int2*    ebin  = (int2*)bufA;   // 782*3072*8 = 19.2 MB <= 25.6 MB; dead before first k_agg

    hipMemsetAsync(gcur, 0, (size_t)NBUCK * 4, stream);

    k_pre<<<691 + 12512, 256, 0, stream>>>(x, srcA, dstA,
                                           c1_w1, c1_w2, c2_w1, c2_w2, c3_w1, c3_w2,
                                           c1_b1, c1_g, c1_be, c1_b2,
                                           c2_b1, c2_g, c2_be, c2_b2,
                                           c3_b1, c3_g, c3_be, c3_b2,
                                           gcur, ebin, Wt, addv, bufC, bufB, pbuf);
    kb_build<<<NBUCK, 256, 0, stream>>>(ebin, gcur, colA, pst, pen);

    // L0: bufC -> (agg) bufA -> (fused gemm+pool) bufB ; L1: bufB -> bufA -> bufC ; L2: bufC -> bufA -> (pool only)
    k_agg<<<MPAD / 4, 256, 0, stream>>>(bufC, pst, pen, colA, bufA);
    k_gemm_f<<<MPAD / 64, 256, 0, stream>>>(bufA, Wt + 0 * 16384, addv + 0 * 128,
                                            Wt + 1 * 16384, addv + 1 * 128, bufB, batch, pbuf, 0);
    k_agg<<<MPAD / 4, 256, 0, stream>>>(bufB, pst, pen, colA, bufA);
    k_gemm_f<<<MPAD / 64, 256, 0, stream>>>(bufA, Wt + 2 * 16384, addv + 2 * 128,
                                            Wt + 3 * 16384, addv + 3 * 128, bufC, batch, pbuf, 128);
    k_agg<<<MPAD / 4, 256, 0, stream>>>(bufC, pst, pen, colA, bufA);
    k_gemm_f<<<MPAD / 64, 256, 0, stream>>>(bufA, Wt + 4 * 16384, addv + 4 * 128,
                                            Wt + 5 * 16384, addv + 5 * 128, (ushortT*)nullptr, batch, pbuf, 256);

    k_head<<<N_GRAPHS, 384, 0, stream>>>(pbuf, l1w, l1b, l2w, l2b, out);
}

// Round 11
// 500.104 us; speedup vs baseline: 1.6584x; 1.0322x over previous
//
#include <hip/hip_runtime.h>

#define N_NODES 100000
#define N_EDGES 1600000
#define N_GRAPHS 512
#define MPAD 100096      // 782 * 128 (also 1564 * 64)
#define NBUCK 782        // buckets of 128 nodes (dst >> 7)
#define BCAP 3072        // per-bucket ebin capacity; mean 2046, sigma ~45 -> 22 sigma margin
#define BCOL 3968        // per-bucket col window: BCAP + 7*128 pad worst case

typedef unsigned short ushortT;
typedef __attribute__((ext_vector_type(8))) short bf16x8;
typedef __attribute__((ext_vector_type(4))) float f32x4;
typedef __attribute__((ext_vector_type(4))) unsigned int uint4v;

__device__ inline float bf2f(ushortT u) {
    unsigned int x = ((unsigned int)u) << 16;
    return __builtin_bit_cast(float, x);
}
__device__ inline ushortT f2bf(float f) {
    unsigned int x = __builtin_bit_cast(unsigned int, f);
    unsigned int r = (x + 0x7fffu + ((x >> 16) & 1u)) >> 16;
    return (ushortT)r;
}

// ======== PROLOGUE (streaming roles only): weight-prep | pbuf zero | bufB pad zero | gcur zero | cvt
__global__ __launch_bounds__(256) void k_pre_rest(
    const float* __restrict__ x,
    const float* __restrict__ w11, const float* __restrict__ w12,
    const float* __restrict__ w21, const float* __restrict__ w22,
    const float* __restrict__ w31, const float* __restrict__ w32,
    const float* __restrict__ b11, const float* __restrict__ g1, const float* __restrict__ be1, const float* __restrict__ b12,
    const float* __restrict__ b21, const float* __restrict__ g2, const float* __restrict__ be2, const float* __restrict__ b22,
    const float* __restrict__ b31, const float* __restrict__ g3, const float* __restrict__ be3, const float* __restrict__ b32,
    int* __restrict__ gcur,
    ushortT* __restrict__ Wt, float* __restrict__ addv,
    ushortT* __restrict__ Ybf, ushortT* __restrict__ bufB, float* __restrict__ pbuf)
{
    int bid = blockIdx.x, t = threadIdx.x;
    if (bid < 386) {
        // -------- weight transpose (fold BN scale) + add vectors --------
        const float rs = rsqrtf(1.0f + 1e-5f);
        if (bid < 384) {
            int idx = bid * 256 + t;
            int m = idx >> 14;
            int r = idx & 16383;
            int k = r & 127;
            int n = r >> 7;
            const float* W = (m == 0) ? w11 : (m == 1) ? w12 : (m == 2) ? w21
                           : (m == 3) ? w22 : (m == 4) ? w31 : w32;
            float v = W[k * 128 + n];
            if ((m & 1) == 0) {
                const float* gm = (m == 0) ? g1 : (m == 2) ? g2 : g3;
                v *= gm[n] * rs;
            }
            Wt[m * 16384 + n * 128 + k] = f2bf(v);
        } else if (bid == 384) {
            if (t < 384) {
                int L = t >> 7, n = t & 127;
                const float* bb = (L == 0) ? b11 : (L == 1) ? b21 : b31;
                const float* gm = (L == 0) ? g1 : (L == 1) ? g2 : g3;
                const float* be = (L == 0) ? be1 : (L == 1) ? be2 : be3;
                float s = gm[n] * rs;
                addv[(2 * L) * 128 + n] = bb[n] * s + be[n];
            }
        } else {
            if (t < 384) {
                int L = t >> 7, n = t & 127;
                const float* bb = (L == 0) ? b12 : (L == 1) ? b22 : b32;
                addv[(2 * L + 1) * 128 + n] = bb[n];
            }
        }
    } else if (bid < 434) {
        // -------- zero pbuf (512*384 fp32 = 48 blocks x 256 x float4) --------
        int i4 = (bid - 386) * 256 + t;
        *(float4*)&pbuf[i4 * 4] = make_float4(0.f, 0.f, 0.f, 0.f);
    } else if (bid == 434) {
        // -------- zero bufB pad rows [N_NODES, MPAD): 96 rows = 1536 u64 --------
        unsigned long long* p = (unsigned long long*)(bufB + (size_t)N_NODES * 128);
#pragma unroll
        for (int i = 0; i < 6; ++i) p[t + i * 256] = 0ull;
    } else if (bid == 435) {
        // -------- zero gcur (782 ints) --------
        for (int i = t; i < NBUCK; i += 256) gcur[i] = 0;
    } else {
        // -------- x (fp32) -> bf16 + zero pad rows --------
        size_t i = ((size_t)(bid - 436) * 256 + t) * 4;
        unsigned long long o = 0ull;
        if (i < (size_t)N_NODES * 128) {
            float4 v = *(const float4*)&x[i];
            o = (unsigned long long)f2bf(v.x)
              | ((unsigned long long)f2bf(v.y) << 16)
              | ((unsigned long long)f2bf(v.z) << 32)
              | ((unsigned long long)f2bf(v.w) << 48);
        }
        *(unsigned long long*)&Ybf[i] = o;
    }
}

// ======== edge scatter into dst-range buckets; 1024 threads/block for TLP in the tail ========
__global__ __launch_bounds__(1024) void k_scatter(const int* __restrict__ src, const int* __restrict__ dst,
                                                  int* __restrict__ gcur, int2* __restrict__ ebin) {
    __shared__ int lcnt[NBUCK];
    __shared__ int lbase[NBUCK];
    int t = threadIdx.x;
    int e0 = blockIdx.x * (N_EDGES / 256);
    int e1 = e0 + (N_EDGES / 256);
    for (int i = t; i < NBUCK; i += 1024) lcnt[i] = 0;
    __syncthreads();
    for (int e = e0 + t; e < e1; e += 1024) atomicAdd(&lcnt[dst[e] >> 7], 1);
    __syncthreads();
    for (int i = t; i < NBUCK; i += 1024) {
        int c = lcnt[i];
        lbase[i] = c ? atomicAdd(&gcur[i], c) : 0;
    }
    __syncthreads();
    for (int i = t; i < NBUCK; i += 1024) lcnt[i] = 0;
    __syncthreads();
    for (int e = e0 + t; e < e1; e += 1024) {
        int d = dst[e];
        int b = d >> 7;
        int off = atomicAdd(&lcnt[b], 1);
        ebin[(size_t)b * BCAP + lbase[b] + off] = make_int2(src[e], d);
    }
}

// ======== per-bucket CSR build: histogram + LDS scan + place + pad ========
__global__ __launch_bounds__(256) void kb_build(const int2* __restrict__ ebin, const int* __restrict__ gcur,
                                                int* __restrict__ col, int* __restrict__ pstart,
                                                int* __restrict__ pend) {
    __shared__ int cnt[128];
    __shared__ int pc[128];
    __shared__ int ps[128];
    __shared__ int cur[128];
    int b = blockIdx.x, t = threadIdx.x;
    if (t < 128) cnt[t] = 0;
    __syncthreads();
    int m = gcur[b];
    const int2* eb = ebin + (size_t)b * BCAP;
    for (int e = t; e < m; e += 256) atomicAdd(&cnt[eb[e].y & 127], 1);
    __syncthreads();
    if (t < 128) pc[t] = (cnt[t] + 7) & ~7;      // padded degree
    __syncthreads();
    for (int off = 1; off < 128; off <<= 1) {    // inclusive scan
        int v = (t < 128 && t >= off) ? pc[t - off] : 0;
        __syncthreads();
        if (t < 128) pc[t] += v;
        __syncthreads();
    }
    if (t < 128) {
        int padded = (cnt[t] + 7) & ~7;
        int start = b * BCOL + pc[t] - padded;   // exclusive prefix
        ps[t] = start;
        cur[t] = 0;
        int node = b * 128 + t;
        if (node < N_NODES) {
            pstart[node] = start;
            pend[node] = start + padded;
        }
    }
    __syncthreads();
    for (int e = t; e < m; e += 256) {
        int2 sd = eb[e];
        int idx = sd.y & 127;
        int pos = ps[idx] + atomicAdd(&cur[idx], 1);
        col[pos] = sd.x;
    }
    __syncthreads();
    if (t < 128) {
        int s = ps[t] + cnt[t];
        int e = ps[t] + ((cnt[t] + 7) & ~7);
        for (int j = s; j < e; ++j) col[j] = N_NODES;   // pad with guaranteed-zero row
    }
}

// ------- aggregation (bf16): T[i] = bf16(X[i] + sum_j X[col[j]]), unroll-8 branch-free -------
__global__ __launch_bounds__(256) void k_agg(const ushortT* __restrict__ X, const int* __restrict__ pstart,
                                             const int* __restrict__ pend, const int* __restrict__ col,
                                             ushortT* __restrict__ T) {
    int gid = blockIdx.x * 4 + (threadIdx.x >> 6);
    int lane = threadIdx.x & 63;
    if (gid >= MPAD) return;
    if (gid >= N_NODES) {                    // zero padding rows (MFMA A-operand hygiene)
        *(unsigned int*)&T[(size_t)gid * 128 + lane * 2] = 0u;
        return;
    }
    int lo = pstart[gid], hi = pend[gid];
    unsigned int v = *(const unsigned int*)&X[(size_t)gid * 128 + lane * 2];
    float ax = bf2f((ushortT)(v & 0xffff));
    float ay = bf2f((ushortT)(v >> 16));
    for (int j = lo; j < hi; j += 8) {       // (hi-lo) % 8 == 0 by construction
        int4 c0 = *(const int4*)&col[j];
        int4 c1 = *(const int4*)&col[j + 4];
        unsigned int u0 = *(const unsigned int*)&X[(size_t)c0.x * 128 + lane * 2];
        unsigned int u1 = *(const unsigned int*)&X[(size_t)c0.y * 128 + lane * 2];
        unsigned int u2 = *(const unsigned int*)&X[(size_t)c0.z * 128 + lane * 2];
        unsigned int u3 = *(const unsigned int*)&X[(size_t)c0.w * 128 + lane * 2];
        unsigned int u4 = *(const unsigned int*)&X[(size_t)c1.x * 128 + lane * 2];
        unsigned int u5 = *(const unsigned int*)&X[(size_t)c1.y * 128 + lane * 2];
        unsigned int u6 = *(const unsigned int*)&X[(size_t)c1.z * 128 + lane * 2];
        unsigned int u7 = *(const unsigned int*)&X[(size_t)c1.w * 128 + lane * 2];
        ax += bf2f((ushortT)(u0 & 0xffff)) + bf2f((ushortT)(u1 & 0xffff))
            + bf2f((ushortT)(u2 & 0xffff)) + bf2f((ushortT)(u3 & 0xffff))
            + bf2f((ushortT)(u4 & 0xffff)) + bf2f((ushortT)(u5 & 0xffff))
            + bf2f((ushortT)(u6 & 0xffff)) + bf2f((ushortT)(u7 & 0xffff));
        ay += bf2f((ushortT)(u0 >> 16)) + bf2f((ushortT)(u1 >> 16))
            + bf2f((ushortT)(u2 >> 16)) + bf2f((ushortT)(u3 >> 16))
            + bf2f((ushortT)(u4 >> 16)) + bf2f((ushortT)(u5 >> 16))
            + bf2f((ushortT)(u6 >> 16)) + bf2f((ushortT)(u7 >> 16));
    }
    unsigned int o = ((unsigned int)f2bf(ay) << 16) | (unsigned int)f2bf(ax);
    *(unsigned int*)&T[(size_t)gid * 128 + lane * 2] = o;
}

// ======== FUSED DOUBLE-GEMM + POOL: C = relu(relu(A@W1+add1)@W2+add2); pool into P.
__global__ __launch_bounds__(256) void k_gemm_f(const ushortT* __restrict__ A,
                                                const ushortT* __restrict__ W1, const float* __restrict__ add1,
                                                const ushortT* __restrict__ W2, const float* __restrict__ add2,
                                                ushortT* __restrict__ C, const int* __restrict__ batch,
                                                float* __restrict__ P, int off) {
    __shared__ ushortT wlds[128 * 136];      // staged weights (reused: W1 -> W2)
    __shared__ ushortT hlds[64 * 136];       // A then H tile; first 3KB reused as pool buffer
    float* pws = (float*)hlds;               // 6 slots x 128 fp32
    int tid = threadIdx.x;
    int wave = tid >> 6, lane = tid & 63;
    int quad = lane >> 4, l16 = lane & 15;
    int blk0 = blockIdx.x * 64;
    int base = blk0 + wave * 16;
    ushortT* hw = hlds + (wave * 16) * 136;

    // stage A into wave-private LDS window (coalesced 1KB per instruction)
    {
        int r = lane >> 4;
        int ck = (lane & 15) * 8;
#pragma unroll
        for (int i = 0; i < 4; ++i) {
            int row = i * 4 + r;
            uint4v v = *(const uint4v*)&A[(size_t)(base + row) * 128 + ck];
            *(uint4v*)&hw[row * 136 + ck] = v;
        }
    }
    // stage W1 (cooperative)
#pragma unroll
    for (int it = 0; it < 8; ++it) {
        int idx = (it * 256 + tid) * 8;
        int n = idx >> 7, k = idx & 127;
        *(uint4v*)&wlds[n * 136 + k] = *(const uint4v*)&W1[idx];
    }
    __syncthreads();

    bf16x8 af[4];
#pragma unroll
    for (int kc = 0; kc < 4; ++kc)
        af[kc] = *(const bf16x8*)&hw[l16 * 136 + kc * 32 + quad * 8];

    // gemm1
    f32x4 acc[8];
#pragma unroll
    for (int c = 0; c < 8; ++c) acc[c] = (f32x4){0.f, 0.f, 0.f, 0.f};
#pragma unroll
    for (int kc = 0; kc < 4; ++kc) {
#pragma unroll
        for (int c = 0; c < 8; ++c) {
            bf16x8 b1 = *(const bf16x8*)&wlds[(c * 16 + l16) * 136 + kc * 32 + quad * 8];
            acc[c] = __builtin_amdgcn_mfma_f32_16x16x32_bf16(af[kc], b1, acc[c], 0, 0, 0);
        }
    }
    __syncthreads();                         // all waves done reading W1

    // stage W2 over W1; write H = relu(acc+add1) over own A window
#pragma unroll
    for (int it = 0; it < 8; ++it) {
        int idx = (it * 256 + tid) * 8;
        int n = idx >> 7, k = idx & 127;
        *(uint4v*)&wlds[n * 136 + k] = *(const uint4v*)&W2[idx];
    }
#pragma unroll
    for (int c = 0; c < 8; ++c) {
        int n = c * 16 + l16;
        float ad = add1[n];
#pragma unroll
        for (int r = 0; r < 4; ++r) {
            float y = acc[c][r] + ad;
            y = y > 0.f ? y : 0.f;
            hw[(quad * 4 + r) * 136 + n] = f2bf(y);
        }
    }
    __syncthreads();                         // W2 staged, H tiles written

#pragma unroll
    for (int kc = 0; kc < 4; ++kc)
        af[kc] = *(const bf16x8*)&hw[l16 * 136 + kc * 32 + quad * 8];
    __syncthreads();                         // H frags in regs -> hlds reusable as pool buf

    for (int i = tid; i < 6 * 128; i += 256) pws[i] = 0.f;
    __syncthreads();

    // gemm2
#pragma unroll
    for (int c = 0; c < 8; ++c) acc[c] = (f32x4){0.f, 0.f, 0.f, 0.f};
#pragma unroll
    for (int kc = 0; kc < 4; ++kc) {
#pragma unroll
        for (int c = 0; c < 8; ++c) {
            bf16x8 b2 = *(const bf16x8*)&wlds[(c * 16 + l16) * 136 + kc * 32 + quad * 8];
            acc[c] = __builtin_amdgcn_mfma_f32_16x16x32_bf16(af[kc], b2, acc[c], 0, 0, 0);
        }
    }

    // epilogue: optional store C; accumulate pool partials
    int g0blk = batch[blk0 < N_NODES ? blk0 : (N_NODES - 1)];
    bool anyrow = (base < N_NODES);
    int gr[4] = {-1, -1, -1, -1};
    if (anyrow) {
#pragma unroll
        for (int r = 0; r < 4; ++r) {
            int row = base + quad * 4 + r;
            gr[r] = (row < N_NODES) ? batch[row] : -1;
        }
    }
    bool fast = (base + 15 < N_NODES) && (batch[base] == batch[base + 15]);

#pragma unroll
    for (int c = 0; c < 8; ++c) {
        int n = c * 16 + l16;
        float ad = add2[n];
        float ys[4];
        float s = 0.f;
#pragma unroll
        for (int r = 0; r < 4; ++r) {
            int row = base + quad * 4 + r;
            float y = 0.f;
            if (row < N_NODES) {
                y = acc[c][r] + ad;
                y = y > 0.f ? y : 0.f;
                if (C) C[(size_t)row * 128 + n] = f2bf(y);
            }
            ys[r] = y;
            s += y;
        }
        if (fast) {
            s += __shfl_xor(s, 16);
            s += __shfl_xor(s, 32);
            if (quad == 0) {
                int slot = gr[0] - g0blk;
                if (slot < 6) atomicAdd(&pws[slot * 128 + n], s);
                else atomicAdd(&P[gr[0] * 384 + off + n], s);
            }
        } else if (anyrow) {
#pragma unroll
            for (int r = 0; r < 4; ++r) {
                if (gr[r] >= 0) {
                    int slot = gr[r] - g0blk;
                    if (slot < 6) atomicAdd(&pws[slot * 128 + n], ys[r]);
                    else atomicAdd(&P[gr[r] * 384 + off + n], ys[r]);
                }
            }
        }
    }
    __syncthreads();

    // flush pool partials
    for (int i = tid; i < 6 * 128; i += 256) {
        float v = pws[i];
        if (v != 0.f) {
            int g = g0blk + (i >> 7);
            atomicAdd(&P[g * 384 + off + (i & 127)], v);
        }
    }
}

// ---------------- head: out = relu(P @ W1 + b1) @ W2 + b2  (all fp32) ------------
__global__ __launch_bounds__(384) void k_head(const float* __restrict__ P, const float* __restrict__ W1,
                                              const float* __restrict__ B1, const float* __restrict__ W2,
                                              const float* __restrict__ B2, float* __restrict__ out) {
    __shared__ float pr[384];
    __shared__ float qr[384];
    int g = blockIdx.x, t = threadIdx.x;
    pr[t] = P[g * 384 + t];
    __syncthreads();
    float a = 0.f;
    for (int k = 0; k < 384; ++k) a += pr[k] * W1[k * 384 + t];
    a += B1[t];
    qr[t] = a > 0.f ? a : 0.f;
    __syncthreads();
    if (t < 10) {
        float o = 0.f;
        for (int k = 0; k < 384; ++k) o += qr[k] * W2[k * 10 + t];
        o += B2[t];
        out[g * 10 + t] = o;
    }
}

extern "C" void kernel_launch(void* const* d_in, const int* in_sizes, int n_in,
                              void* d_out, int out_size, void* d_ws, size_t ws_size,
                              hipStream_t stream) {
    const float* x     = (const float*)d_in[0];
    const int*   ei    = (const int*)d_in[1];
    const int*   srcA  = ei;
    const int*   dstA  = ei + N_EDGES;
    const int*   batch = (const int*)d_in[2];
    const float* c1_w1 = (const float*)d_in[3];
    const float* c1_b1 = (const float*)d_in[4];
    const float* c1_g  = (const float*)d_in[5];
    const float* c1_be = (const float*)d_in[6];
    const float* c1_w2 = (const float*)d_in[7];
    const float* c1_b2 = (const float*)d_in[8];
    const float* c2_w1 = (const float*)d_in[9];
    const float* c2_b1 = (const float*)d_in[10];
    const float* c2_g  = (const float*)d_in[11];
    const float* c2_be = (const float*)d_in[12];
    const float* c2_w2 = (const float*)d_in[13];
    const float* c2_b2 = (const float*)d_in[14];
    const float* c3_w1 = (const float*)d_in[15];
    const float* c3_b1 = (const float*)d_in[16];
    const float* c3_g  = (const float*)d_in[17];
    const float* c3_be = (const float*)d_in[18];
    const float* c3_w2 = (const float*)d_in[19];
    const float* c3_b2 = (const float*)d_in[20];
    const float* l1w   = (const float*)d_in[21];
    const float* l1b   = (const float*)d_in[22];
    const float* l2w   = (const float*)d_in[23];
    const float* l2b   = (const float*)d_in[24];
    float* out = (float*)d_out;

    size_t o = 0;
    char* base = (char*)d_ws;
    auto alloc = [&](size_t n) -> char* {
        char* p = base + o;
        o += (n + 255) & ~(size_t)255;
        return p;
    };
    ushortT* Wt    = (ushortT*)alloc(6 * 16384 * 2);
    float*   addv  = (float*)alloc(6 * 128 * 4);
    int*     gcur  = (int*)alloc((size_t)NBUCK * 4);
    int*     pst   = (int*)alloc((size_t)N_NODES * 4);
    int*     pen   = (int*)alloc((size_t)N_NODES * 4);
    int*     colA  = (int*)alloc((size_t)NBUCK * BCOL * 4);
    ushortT* bufA  = (ushortT*)alloc((size_t)MPAD * 128 * 2);   // agg out; ebin aliases this
    ushortT* bufB  = (ushortT*)alloc((size_t)MPAD * 128 * 2);   // L0 out
    ushortT* bufC  = (ushortT*)alloc((size_t)MPAD * 128 * 2);   // x(bf16) / L1 out
    float*   pbuf  = (float*)alloc((size_t)N_GRAPHS * 384 * 4);
    int2*    ebin  = (int2*)bufA;   // 19.2 MB <= 25.6 MB; dead before first k_agg

    k_pre_rest<<<436 + 12512, 256, 0, stream>>>(x,
                                                c1_w1, c1_w2, c2_w1, c2_w2, c3_w1, c3_w2,
                                                c1_b1, c1_g, c1_be, c1_b2,
                                                c2_b1, c2_g, c2_be, c2_b2,
                                                c3_b1, c3_g, c3_be, c3_b2,
                                                gcur, Wt, addv, bufC, bufB, pbuf);
    k_scatter<<<256, 1024, 0, stream>>>(srcA, dstA, gcur, ebin);
    kb_build<<<NBUCK, 256, 0, stream>>>(ebin, gcur, colA, pst, pen);

    // L0: bufC -> (agg) bufA -> (fused gemm+pool) bufB ; L1: bufB -> bufA -> bufC ; L2: bufC -> bufA -> (pool only)
    k_agg<<<MPAD / 4, 256, 0, stream>>>(bufC, pst, pen, colA, bufA);
    k_gemm_f<<<MPAD / 64, 256, 0, stream>>>(bufA, Wt + 0 * 16384, addv + 0 * 128,
                                            Wt + 1 * 16384, addv + 1 * 128, bufB, batch, pbuf, 0);
    k_agg<<<MPAD / 4, 256, 0, stream>>>(bufB, pst, pen, colA, bufA);
    k_gemm_f<<<MPAD / 64, 256, 0, stream>>>(bufA, Wt + 2 * 16384, addv + 2 * 128,
                                            Wt + 3 * 16384, addv + 3 * 128, bufC, batch, pbuf, 128);
    k_agg<<<MPAD / 4, 256, 0, stream>>>(bufC, pst, pen, colA, bufA);
    k_gemm_f<<<MPAD / 64, 256, 0, stream>>>(bufA, Wt + 4 * 16384, addv + 4 * 128,
                                            Wt + 5 * 16384, addv + 5 * 128, (ushortT*)nullptr, batch, pbuf, 256);

    k_head<<<N_GRAPHS, 384, 0, stream>>>(pbuf, l1w, l1b, l2w, l2b, out);
}

// Round 12
// 443.036 us; speedup vs baseline: 1.8720x; 1.1288x over previous
//
#include <hip/hip_runtime.h>

#define N_NODES 100000
#define N_EDGES 1600000
#define N_GRAPHS 512
#define MPAD 100096      // 782 * 128 (also 1564 * 64)
#define NBUCK 782        // buckets of 128 nodes (dst >> 7)
#define BCAP 3072        // per-bucket ebin capacity; mean 2046, sigma ~45 -> 22 sigma margin
#define BCOL 3968        // per-bucket col window: BCAP + 7*128 pad worst case

typedef unsigned short ushortT;
typedef unsigned char u8;
typedef __attribute__((ext_vector_type(8))) short bf16x8;
typedef __attribute__((ext_vector_type(4))) float f32x4;
typedef __attribute__((ext_vector_type(2))) float f32x2;
typedef __attribute__((ext_vector_type(4))) unsigned int uint4v;

__device__ inline float bf2f(ushortT u) {
    unsigned int x = ((unsigned int)u) << 16;
    return __builtin_bit_cast(float, x);
}
__device__ inline ushortT f2bf(float f) {
    unsigned int x = __builtin_bit_cast(unsigned int, f);
    unsigned int r = (x + 0x7fffu + ((x >> 16) & 1u)) >> 16;
    return (ushortT)r;
}

// ---------------- fp8 e4m3 conversion (HW cvt on gfx950; manual fallback) ----------------
#if defined(__has_builtin)
#if __has_builtin(__builtin_amdgcn_cvt_pk_f32_fp8) && __has_builtin(__builtin_amdgcn_cvt_pk_fp8_f32)
#define HW_FP8 1
#endif
#endif

__device__ inline f32x2 fp8x2_f32(unsigned short u) {
#ifdef HW_FP8
    return __builtin_amdgcn_cvt_pk_f32_fp8((int)(unsigned int)u, false);
#else
    f32x2 r;
#pragma unroll
    for (int i = 0; i < 2; ++i) {
        unsigned int b = (u >> (8 * i)) & 0xFFu;
        unsigned int s = (b >> 7) << 31;
        unsigned int em = b & 0x7Fu;
        float v;
        if (em == 0) v = 0.f;
        else if ((em >> 3) == 0) v = (float)(em & 7) * 0.001953125f;   // subnormal m/8 * 2^-6
        else {
            unsigned int f32b = ((((em >> 3) - 7 + 127)) << 23) | ((em & 7) << 20);
            v = __builtin_bit_cast(float, f32b);
        }
        r[i] = __builtin_bit_cast(float, __builtin_bit_cast(unsigned int, v) | s);
    }
    return r;
#endif
}

#ifndef HW_FP8
__device__ inline u8 f2fp8_sw(float f) {
    unsigned int b = __builtin_bit_cast(unsigned int, f);
    u8 s = (u8)((b >> 24) & 0x80);
    float a = __builtin_bit_cast(float, b & 0x7FFFFFFF);
    if (a >= 448.f) return s | 0x7E;
    if (a < 0.0078125f) return s;            // flush < 2^-7
    unsigned int ab = __builtin_bit_cast(unsigned int, a);
    ab += 0x0007FFFF + ((ab >> 20) & 1);     // RTNE at bit 20
    int e = (int)((ab >> 23) & 0xFF) - 120;
    if (e >= 16) return s | 0x7E;
    if (e <= 0) return s;
    return s | (u8)((e << 3) | ((ab >> 20) & 7));
}
#endif

__device__ inline unsigned int f32x2_fp8(float a, float b) {     // 2 bytes in low 16
#ifdef HW_FP8
    return (unsigned int)__builtin_amdgcn_cvt_pk_fp8_f32(a, b, 0, false) & 0xFFFFu;
#else
    return (unsigned int)f2fp8_sw(a) | ((unsigned int)f2fp8_sw(b) << 8);
#endif
}
__device__ inline u8 f2fp8(float y) {
#ifdef HW_FP8
    return (u8)(__builtin_amdgcn_cvt_pk_fp8_f32(y, y, 0, false) & 0xFF);
#else
    return f2fp8_sw(y);
#endif
}

// ======== PROLOGUE: weight-prep | pbuf zero | C pad-row zero | gcur zero | x->fp8 cvt ========
__global__ __launch_bounds__(256) void k_pre_rest(
    const float* __restrict__ x,
    const float* __restrict__ w11, const float* __restrict__ w12,
    const float* __restrict__ w21, const float* __restrict__ w22,
    const float* __restrict__ w31, const float* __restrict__ w32,
    const float* __restrict__ b11, const float* __restrict__ g1, const float* __restrict__ be1, const float* __restrict__ b12,
    const float* __restrict__ b21, const float* __restrict__ g2, const float* __restrict__ be2, const float* __restrict__ b22,
    const float* __restrict__ b31, const float* __restrict__ g3, const float* __restrict__ be3, const float* __restrict__ b32,
    int* __restrict__ gcur,
    ushortT* __restrict__ Wt, float* __restrict__ addv,
    u8* __restrict__ Xf8, u8* __restrict__ C0, u8* __restrict__ C1, float* __restrict__ pbuf)
{
    int bid = blockIdx.x, t = threadIdx.x;
    if (bid < 386) {
        const float rs = rsqrtf(1.0f + 1e-5f);
        if (bid < 384) {
            int idx = bid * 256 + t;
            int m = idx >> 14;
            int r = idx & 16383;
            int k = r & 127;
            int n = r >> 7;
            const float* W = (m == 0) ? w11 : (m == 1) ? w12 : (m == 2) ? w21
                           : (m == 3) ? w22 : (m == 4) ? w31 : w32;
            float v = W[k * 128 + n];
            if ((m & 1) == 0) {
                const float* gm = (m == 0) ? g1 : (m == 2) ? g2 : g3;
                v *= gm[n] * rs;
            }
            Wt[m * 16384 + n * 128 + k] = f2bf(v);
        } else if (bid == 384) {
            if (t < 384) {
                int L = t >> 7, n = t & 127;
                const float* bb = (L == 0) ? b11 : (L == 1) ? b21 : b31;
                const float* gm = (L == 0) ? g1 : (L == 1) ? g2 : g3;
                const float* be = (L == 0) ? be1 : (L == 1) ? be2 : be3;
                float s = gm[n] * rs;
                addv[(2 * L) * 128 + n] = bb[n] * s + be[n];
            }
        } else {
            if (t < 384) {
                int L = t >> 7, n = t & 127;
                const float* bb = (L == 0) ? b12 : (L == 1) ? b22 : b32;
                addv[(2 * L + 1) * 128 + n] = bb[n];
            }
        }
    } else if (bid < 434) {
        int i4 = (bid - 386) * 256 + t;
        *(float4*)&pbuf[i4 * 4] = make_float4(0.f, 0.f, 0.f, 0.f);
    } else if (bid == 434) {
        // zero pad row (index N_NODES) of C0 and C1: 128 B each
        if (t < 32) *(unsigned int*)&C0[(size_t)N_NODES * 128 + t * 4] = 0u;
        else if (t < 64) *(unsigned int*)&C1[(size_t)N_NODES * 128 + (t - 32) * 4] = 0u;
    } else if (bid == 435) {
        for (int i = t; i < NBUCK; i += 256) gcur[i] = 0;
    } else {
        // x (fp32) -> fp8, zero pad rows
        size_t i = ((size_t)(bid - 436) * 256 + t) * 4;   // element index
        unsigned int o = 0u;
        if (i < (size_t)N_NODES * 128) {
            float4 v = *(const float4*)&x[i];
            o = f32x2_fp8(v.x, v.y) | (f32x2_fp8(v.z, v.w) << 16);
        }
        *(unsigned int*)&Xf8[i] = o;
    }
}

// ======== edge scatter into dst-range buckets; 1024 threads/block ========
__global__ __launch_bounds__(1024) void k_scatter(const int* __restrict__ src, const int* __restrict__ dst,
                                                  int* __restrict__ gcur, int2* __restrict__ ebin) {
    __shared__ int lcnt[NBUCK];
    __shared__ int lbase[NBUCK];
    int t = threadIdx.x;
    int e0 = blockIdx.x * (N_EDGES / 256);
    int e1 = e0 + (N_EDGES / 256);
    for (int i = t; i < NBUCK; i += 1024) lcnt[i] = 0;
    __syncthreads();
    for (int e = e0 + t; e < e1; e += 1024) atomicAdd(&lcnt[dst[e] >> 7], 1);
    __syncthreads();
    for (int i = t; i < NBUCK; i += 1024) {
        int c = lcnt[i];
        lbase[i] = c ? atomicAdd(&gcur[i], c) : 0;
    }
    __syncthreads();
    for (int i = t; i < NBUCK; i += 1024) lcnt[i] = 0;
    __syncthreads();
    for (int e = e0 + t; e < e1; e += 1024) {
        int d = dst[e];
        int b = d >> 7;
        int off = atomicAdd(&lcnt[b], 1);
        ebin[(size_t)b * BCAP + lbase[b] + off] = make_int2(src[e], d);
    }
}

// ======== per-bucket CSR build: histogram + LDS scan + place + pad ========
__global__ __launch_bounds__(256) void kb_build(const int2* __restrict__ ebin, const int* __restrict__ gcur,
                                                int* __restrict__ col, int* __restrict__ pstart,
                                                int* __restrict__ pend) {
    __shared__ int cnt[128];
    __shared__ int pc[128];
    __shared__ int ps[128];
    __shared__ int cur[128];
    int b = blockIdx.x, t = threadIdx.x;
    if (t < 128) cnt[t] = 0;
    __syncthreads();
    int m = gcur[b];
    const int2* eb = ebin + (size_t)b * BCAP;
    for (int e = t; e < m; e += 256) atomicAdd(&cnt[eb[e].y & 127], 1);
    __syncthreads();
    if (t < 128) pc[t] = (cnt[t] + 7) & ~7;
    __syncthreads();
    for (int off = 1; off < 128; off <<= 1) {
        int v = (t < 128 && t >= off) ? pc[t - off] : 0;
        __syncthreads();
        if (t < 128) pc[t] += v;
        __syncthreads();
    }
    if (t < 128) {
        int padded = (cnt[t] + 7) & ~7;
        int start = b * BCOL + pc[t] - padded;
        ps[t] = start;
        cur[t] = 0;
        int node = b * 128 + t;
        if (node < N_NODES) {
            pstart[node] = start;
            pend[node] = start + padded;
        }
    }
    __syncthreads();
    for (int e = t; e < m; e += 256) {
        int2 sd = eb[e];
        int idx = sd.y & 127;
        int pos = ps[idx] + atomicAdd(&cur[idx], 1);
        col[pos] = sd.x;
    }
    __syncthreads();
    if (t < 128) {
        int s = ps[t] + cnt[t];
        int e = ps[t] + ((cnt[t] + 7) & ~7);
        for (int j = s; j < e; ++j) col[j] = N_NODES;
    }
}

// ------- aggregation: T[i](bf16) = X[i] + sum_j X[col[j]], X in fp8 (128B rows = 2 lines/gather) -------
__global__ __launch_bounds__(256) void k_agg(const u8* __restrict__ X, const int* __restrict__ pstart,
                                             const int* __restrict__ pend, const int* __restrict__ col,
                                             ushortT* __restrict__ T) {
    int gid = blockIdx.x * 4 + (threadIdx.x >> 6);
    int lane = threadIdx.x & 63;
    if (gid >= MPAD) return;
    if (gid >= N_NODES) {
        *(unsigned int*)&T[(size_t)gid * 128 + lane * 2] = 0u;
        return;
    }
    int lo = pstart[gid], hi = pend[gid];
    unsigned short v = *(const unsigned short*)&X[(size_t)gid * 128 + lane * 2];
    f32x2 fv = fp8x2_f32(v);
    float ax = fv.x, ay = fv.y;
    for (int j = lo; j < hi; j += 8) {
        int4 c0 = *(const int4*)&col[j];
        int4 c1 = *(const int4*)&col[j + 4];
        unsigned short u0 = *(const unsigned short*)&X[(size_t)c0.x * 128 + lane * 2];
        unsigned short u1 = *(const unsigned short*)&X[(size_t)c0.y * 128 + lane * 2];
        unsigned short u2 = *(const unsigned short*)&X[(size_t)c0.z * 128 + lane * 2];
        unsigned short u3 = *(const unsigned short*)&X[(size_t)c0.w * 128 + lane * 2];
        unsigned short u4 = *(const unsigned short*)&X[(size_t)c1.x * 128 + lane * 2];
        unsigned short u5 = *(const unsigned short*)&X[(size_t)c1.y * 128 + lane * 2];
        unsigned short u6 = *(const unsigned short*)&X[(size_t)c1.z * 128 + lane * 2];
        unsigned short u7 = *(const unsigned short*)&X[(size_t)c1.w * 128 + lane * 2];
        f32x2 f0 = fp8x2_f32(u0), f1 = fp8x2_f32(u1), f2 = fp8x2_f32(u2), f3 = fp8x2_f32(u3);
        f32x2 f4 = fp8x2_f32(u4), f5 = fp8x2_f32(u5), f6 = fp8x2_f32(u6), f7 = fp8x2_f32(u7);
        ax += f0.x + f1.x + f2.x + f3.x + f4.x + f5.x + f6.x + f7.x;
        ay += f0.y + f1.y + f2.y + f3.y + f4.y + f5.y + f6.y + f7.y;
    }
    unsigned int o = ((unsigned int)f2bf(ay) << 16) | (unsigned int)f2bf(ax);
    *(unsigned int*)&T[(size_t)gid * 128 + lane * 2] = o;
}

// ======== FUSED DOUBLE-GEMM + POOL: C(fp8) = relu(relu(A@W1+add1)@W2+add2); pool into P ========
__global__ __launch_bounds__(256) void k_gemm_f(const ushortT* __restrict__ A,
                                                const ushortT* __restrict__ W1, const float* __restrict__ add1,
                                                const ushortT* __restrict__ W2, const float* __restrict__ add2,
                                                u8* __restrict__ C, const int* __restrict__ batch,
                                                float* __restrict__ P, int off) {
    __shared__ ushortT wlds[128 * 136];
    __shared__ ushortT hlds[64 * 136];
    float* pws = (float*)hlds;
    int tid = threadIdx.x;
    int wave = tid >> 6, lane = tid & 63;
    int quad = lane >> 4, l16 = lane & 15;
    int blk0 = blockIdx.x * 64;
    int base = blk0 + wave * 16;
    ushortT* hw = hlds + (wave * 16) * 136;

    // stage A (bf16) into wave-private LDS window
    {
        int r = lane >> 4;
        int ck = (lane & 15) * 8;
#pragma unroll
        for (int i = 0; i < 4; ++i) {
            int row = i * 4 + r;
            uint4v v = *(const uint4v*)&A[(size_t)(base + row) * 128 + ck];
            *(uint4v*)&hw[row * 136 + ck] = v;
        }
    }
#pragma unroll
    for (int it = 0; it < 8; ++it) {
        int idx = (it * 256 + tid) * 8;
        int n = idx >> 7, k = idx & 127;
        *(uint4v*)&wlds[n * 136 + k] = *(const uint4v*)&W1[idx];
    }
    __syncthreads();

    bf16x8 af[4];
#pragma unroll
    for (int kc = 0; kc < 4; ++kc)
        af[kc] = *(const bf16x8*)&hw[l16 * 136 + kc * 32 + quad * 8];

    f32x4 acc[8];
#pragma unroll
    for (int c = 0; c < 8; ++c) acc[c] = (f32x4){0.f, 0.f, 0.f, 0.f};
#pragma unroll
    for (int kc = 0; kc < 4; ++kc) {
#pragma unroll
        for (int c = 0; c < 8; ++c) {
            bf16x8 b1 = *(const bf16x8*)&wlds[(c * 16 + l16) * 136 + kc * 32 + quad * 8];
            acc[c] = __builtin_amdgcn_mfma_f32_16x16x32_bf16(af[kc], b1, acc[c], 0, 0, 0);
        }
    }
    __syncthreads();

#pragma unroll
    for (int it = 0; it < 8; ++it) {
        int idx = (it * 256 + tid) * 8;
        int n = idx >> 7, k = idx & 127;
        *(uint4v*)&wlds[n * 136 + k] = *(const uint4v*)&W2[idx];
    }
#pragma unroll
    for (int c = 0; c < 8; ++c) {
        int n = c * 16 + l16;
        float ad = add1[n];
#pragma unroll
        for (int r = 0; r < 4; ++r) {
            float y = acc[c][r] + ad;
            y = y > 0.f ? y : 0.f;
            hw[(quad * 4 + r) * 136 + n] = f2bf(y);
        }
    }
    __syncthreads();

#pragma unroll
    for (int kc = 0; kc < 4; ++kc)
        af[kc] = *(const bf16x8*)&hw[l16 * 136 + kc * 32 + quad * 8];
    __syncthreads();

    for (int i = tid; i < 6 * 128; i += 256) pws[i] = 0.f;
    __syncthreads();

#pragma unroll
    for (int c = 0; c < 8; ++c) acc[c] = (f32x4){0.f, 0.f, 0.f, 0.f};
#pragma unroll
    for (int kc = 0; kc < 4; ++kc) {
#pragma unroll
        for (int c = 0; c < 8; ++c) {
            bf16x8 b2 = *(const bf16x8*)&wlds[(c * 16 + l16) * 136 + kc * 32 + quad * 8];
            acc[c] = __builtin_amdgcn_mfma_f32_16x16x32_bf16(af[kc], b2, acc[c], 0, 0, 0);
        }
    }

    int g0blk = batch[blk0 < N_NODES ? blk0 : (N_NODES - 1)];
    bool anyrow = (base < N_NODES);
    int gr[4] = {-1, -1, -1, -1};
    if (anyrow) {
#pragma unroll
        for (int r = 0; r < 4; ++r) {
            int row = base + quad * 4 + r;
            gr[r] = (row < N_NODES) ? batch[row] : -1;
        }
    }
    bool fast = (base + 15 < N_NODES) && (batch[base] == batch[base + 15]);

#pragma unroll
    for (int c = 0; c < 8; ++c) {
        int n = c * 16 + l16;
        float ad = add2[n];
        float ys[4];
        float s = 0.f;
#pragma unroll
        for (int r = 0; r < 4; ++r) {
            int row = base + quad * 4 + r;
            float y = 0.f;
            if (row < N_NODES) {
                y = acc[c][r] + ad;
                y = y > 0.f ? y : 0.f;
                if (C) C[(size_t)row * 128 + n] = f2fp8(y);
            }
            ys[r] = y;
            s += y;
        }
        if (fast) {
            s += __shfl_xor(s, 16);
            s += __shfl_xor(s, 32);
            if (quad == 0) {
                int slot = gr[0] - g0blk;
                if (slot < 6) atomicAdd(&pws[slot * 128 + n], s);
                else atomicAdd(&P[gr[0] * 384 + off + n], s);
            }
        } else if (anyrow) {
#pragma unroll
            for (int r = 0; r < 4; ++r) {
                if (gr[r] >= 0) {
                    int slot = gr[r] - g0blk;
                    if (slot < 6) atomicAdd(&pws[slot * 128 + n], ys[r]);
                    else atomicAdd(&P[gr[r] * 384 + off + n], ys[r]);
                }
            }
        }
    }
    __syncthreads();

    for (int i = tid; i < 6 * 128; i += 256) {
        float v = pws[i];
        if (v != 0.f) {
            int g = g0blk + (i >> 7);
            atomicAdd(&P[g * 384 + off + (i & 127)], v);
        }
    }
}

// ---------------- head: out = relu(P @ W1 + b1) @ W2 + b2  (all fp32) ------------
__global__ __launch_bounds__(384) void k_head(const float* __restrict__ P, const float* __restrict__ W1,
                                              const float* __restrict__ B1, const float* __restrict__ W2,
                                              const float* __restrict__ B2, float* __restrict__ out) {
    __shared__ float pr[384];
    __shared__ float qr[384];
    int g = blockIdx.x, t = threadIdx.x;
    pr[t] = P[g * 384 + t];
    __syncthreads();
    float a = 0.f;
    for (int k = 0; k < 384; ++k) a += pr[k] * W1[k * 384 + t];
    a += B1[t];
    qr[t] = a > 0.f ? a : 0.f;
    __syncthreads();
    if (t < 10) {
        float o = 0.f;
        for (int k = 0; k < 384; ++k) o += qr[k] * W2[k * 10 + t];
        o += B2[t];
        out[g * 10 + t] = o;
    }
}

extern "C" void kernel_launch(void* const* d_in, const int* in_sizes, int n_in,
                              void* d_out, int out_size, void* d_ws, size_t ws_size,
                              hipStream_t stream) {
    const float* x     = (const float*)d_in[0];
    const int*   ei    = (const int*)d_in[1];
    const int*   srcA  = ei;
    const int*   dstA  = ei + N_EDGES;
    const int*   batch = (const int*)d_in[2];
    const float* c1_w1 = (const float*)d_in[3];
    const float* c1_b1 = (const float*)d_in[4];
    const float* c1_g  = (const float*)d_in[5];
    const float* c1_be = (const float*)d_in[6];
    const float* c1_w2 = (const float*)d_in[7];
    const float* c1_b2 = (const float*)d_in[8];
    const float* c2_w1 = (const float*)d_in[9];
    const float* c2_b1 = (const float*)d_in[10];
    const float* c2_g  = (const float*)d_in[11];
    const float* c2_be = (const float*)d_in[12];
    const float* c2_w2 = (const float*)d_in[13];
    const float* c2_b2 = (const float*)d_in[14];
    const float* c3_w1 = (const float*)d_in[15];
    const float* c3_b1 = (const float*)d_in[16];
    const float* c3_g  = (const float*)d_in[17];
    const float* c3_be = (const float*)d_in[18];
    const float* c3_w2 = (const float*)d_in[19];
    const float* c3_b2 = (const float*)d_in[20];
    const float* l1w   = (const float*)d_in[21];
    const float* l1b   = (const float*)d_in[22];
    const float* l2w   = (const float*)d_in[23];
    const float* l2b   = (const float*)d_in[24];
    float* out = (float*)d_out;

    size_t o = 0;
    char* base = (char*)d_ws;
    auto alloc = [&](size_t n) -> char* {
        char* p = base + o;
        o += (n + 255) & ~(size_t)255;
        return p;
    };
    ushortT* Wt    = (ushortT*)alloc(6 * 16384 * 2);
    float*   addv  = (float*)alloc(6 * 128 * 4);
    int*     gcur  = (int*)alloc((size_t)NBUCK * 4);
    int*     pst   = (int*)alloc((size_t)N_NODES * 4);
    int*     pen   = (int*)alloc((size_t)N_NODES * 4);
    int*     colA  = (int*)alloc((size_t)NBUCK * BCOL * 4);
    ushortT* T     = (ushortT*)alloc((size_t)MPAD * 128 * 2);   // agg out (bf16); ebin aliases
    u8*      Xf8   = (u8*)alloc((size_t)MPAD * 128);            // x in fp8
    u8*      C0    = (u8*)alloc((size_t)MPAD * 128);            // L0 out fp8
    u8*      C1    = (u8*)alloc((size_t)MPAD * 128);            // L1 out fp8
    float*   pbuf  = (float*)alloc((size_t)N_GRAPHS * 384 * 4);
    int2*    ebin  = (int2*)T;   // 19.2 MB <= 25.6 MB; dead before first k_agg

    k_pre_rest<<<436 + 12512, 256, 0, stream>>>(x,
                                                c1_w1, c1_w2, c2_w1, c2_w2, c3_w1, c3_w2,
                                                c1_b1, c1_g, c1_be, c1_b2,
                                                c2_b1, c2_g, c2_be, c2_b2,
                                                c3_b1, c3_g, c3_be, c3_b2,
                                                gcur, Wt, addv, Xf8, C0, C1, pbuf);
    k_scatter<<<256, 1024, 0, stream>>>(srcA, dstA, gcur, ebin);
    kb_build<<<NBUCK, 256, 0, stream>>>(ebin, gcur, colA, pst, pen);

    // L0: Xf8 -> (agg) T -> (gemm+pool) C0 ; L1: C0 -> T -> C1 ; L2: C1 -> T -> (pool only)
    k_agg<<<MPAD / 4, 256, 0, stream>>>(Xf8, pst, pen, colA, T);
    k_gemm_f<<<MPAD / 64, 256, 0, stream>>>(T, Wt + 0 * 16384, addv + 0 * 128,
                                            Wt + 1 * 16384, addv + 1 * 128, C0, batch, pbuf, 0);
    k_agg<<<MPAD / 4, 256, 0, stream>>>(C0, pst, pen, colA, T);
    k_gemm_f<<<MPAD / 64, 256, 0, stream>>>(T, Wt + 2 * 16384, addv + 2 * 128,
                                            Wt + 3 * 16384, addv + 3 * 128, C1, batch, pbuf, 128);
    k_agg<<<MPAD / 4, 256, 0, stream>>>(C1, pst, pen, colA, T);
    k_gemm_f<<<MPAD / 64, 256, 0, stream>>>(T, Wt + 4 * 16384, addv + 4 * 128,
                                            Wt + 5 * 16384, addv + 5 * 128, (u8*)nullptr, batch, pbuf, 256);

    k_head<<<N_GRAPHS, 384, 0, stream>>>(pbuf, l1w, l1b, l2w, l2b, out);
}